// Round 1
// baseline (2612.702 us; speedup 1.0000x reference)
//
#include <hip/hip_runtime.h>

// Problem constants
#define BB   64
#define SS   512
#define DD   128
#define DFFc 256
#define HH   4
#define TT   9
#define LL   2
#define HDc  32
#define NN   (BB*SS)   // 32768 tokens

// Workspace layout (float offsets)
#define OFF_X    0
#define OFF_Y    (NN*DD)
#define OFF_QKV  (2*NN*DD)          // 3*NN*DD floats; reused for FF hidden (NN*DFFc = 2*NN*DD)
#define OFF_CTX  (5*NN*DD)
#define OFF_KT   (6*NN*DD)
#define OFF_EM   (7*NN*DD)
#define OFF_PART (7*NN*DD + NN*TT)
// total floats = 7*NN*DD + NN*TT + 64 = 29,655,104  (~119 MB)

// ---------------------------------------------------------------------------
// Embedding + sinusoidal positional encoding. x[n][d] = emb[tok][d] (0 if tok==0) + pe[s][d]
__global__ void k_embed(const int* __restrict__ sent, const float* __restrict__ emb,
                        float* __restrict__ x) {
  int n = blockIdx.x;
  int d = threadIdx.x;
  int tok = sent[n];
  int s = n & (SS - 1);
  float e = (tok != 0) ? emb[(size_t)tok * DD + d] : 0.f;
  int i = d >> 1;
  float dv = expf((float)(2 * i) * (-9.210340371976184f / (float)DD)); // -ln(10000)/D
  float ang = (float)s * dv;
  float pe = (d & 1) ? cosf(ang) : sinf(ang);
  x[(size_t)n * DD + d] = e + pe;
}

// ---------------------------------------------------------------------------
// Generic tiled GEMM: Y[n][c] = act( sum_k X[n][k]*W[c][k] + bias[c] )
// Block tile 64 rows x 64 cols, KB=64, 4x4 register tile per thread.
template <int KTOT, bool RELU>
__global__ __launch_bounds__(256) void k_gemm(const float* __restrict__ X,
                                              const float* __restrict__ W,
                                              const float* __restrict__ bias,
                                              float* __restrict__ Y, int ldY) {
  __shared__ float Xs[64][68];   // [row][k], stride 68 -> 2-way max conflicts
  __shared__ float Wt[64][68];   // [k][col] (transposed in LDS)
  const int tid = threadIdx.x;
  const int tx = tid & 15, ty = tid >> 4;   // cols c0=4*tx, rows r0=4*ty
  const int n0 = blockIdx.x * 64, c0g = blockIdx.y * 64;
  float acc[4][4] = {};
  for (int kb = 0; kb < KTOT; kb += 64) {
    // stage X tile (coalesced float4)
    #pragma unroll
    for (int p = 0; p < 4; p++) {
      int r = p * 16 + (tid >> 4);
      int c4 = (tid & 15) * 4;
      *(float4*)&Xs[r][c4] = *(const float4*)&X[(size_t)(n0 + r) * KTOT + kb + c4];
    }
    // stage W transposed: Wt[kk][c] = W[c0g+c][kb+kk]  (2-way write conflicts)
    #pragma unroll
    for (int p = 0; p < 4; p++) {
      int c = (tid >> 4) + 16 * p;
      int kk0 = tid & 15;
      #pragma unroll
      for (int ii = 0; ii < 4; ii++)
        Wt[kk0 + 16 * ii][c] = W[(size_t)(c0g + c) * KTOT + kb + kk0 + 16 * ii];
    }
    __syncthreads();
    #pragma unroll
    for (int k4 = 0; k4 < 16; k4++) {
      float4 a4[4], b4[4];
      #pragma unroll
      for (int i = 0; i < 4; i++) a4[i] = *(const float4*)&Xs[4 * ty + i][4 * k4];
      #pragma unroll
      for (int k = 0; k < 4; k++) b4[k] = *(const float4*)&Wt[4 * k4 + k][4 * tx];
      #pragma unroll
      for (int k = 0; k < 4; k++) {
        #pragma unroll
        for (int i = 0; i < 4; i++) {
          float av = (k == 0) ? a4[i].x : (k == 1) ? a4[i].y : (k == 2) ? a4[i].z : a4[i].w;
          acc[i][0] = fmaf(av, b4[k].x, acc[i][0]);
          acc[i][1] = fmaf(av, b4[k].y, acc[i][1]);
          acc[i][2] = fmaf(av, b4[k].z, acc[i][2]);
          acc[i][3] = fmaf(av, b4[k].w, acc[i][3]);
        }
      }
    }
    __syncthreads();
  }
  float4 bi = *(const float4*)&bias[c0g + 4 * tx];
  #pragma unroll
  for (int i = 0; i < 4; i++) {
    float4 o;
    o.x = acc[i][0] + bi.x; o.y = acc[i][1] + bi.y;
    o.z = acc[i][2] + bi.z; o.w = acc[i][3] + bi.w;
    if (RELU) {
      o.x = fmaxf(o.x, 0.f); o.y = fmaxf(o.y, 0.f);
      o.z = fmaxf(o.z, 0.f); o.w = fmaxf(o.w, 0.f);
    }
    *(float4*)&Y[(size_t)(n0 + 4 * ty + i) * ldY + c0g + 4 * tx] = o;
  }
}

// ---------------------------------------------------------------------------
// GEMM + bias + residual + LayerNorm fused. Block = 32 rows x full 128 cols.
// Y[n][c] = LN( X[n][:]@W[c][:] + bias[c] + Res[n][c] ) * gam[c] + bet[c]
template <int KTOT>
__global__ __launch_bounds__(256) void k_gemm_ln(const float* __restrict__ X,
                                                 const float* __restrict__ W,
                                                 const float* __restrict__ bias,
                                                 const float* __restrict__ Res,
                                                 const float* __restrict__ gam,
                                                 const float* __restrict__ bet,
                                                 float* __restrict__ Y) {
  __shared__ float Xs[32][68];
  __shared__ float Wt[64][132];
  const int tid = threadIdx.x;
  const int tx = tid & 31, ty = tid >> 5;   // cols c0=4*tx (128), rows r0=4*ty (32)
  const int n0 = blockIdx.x * 32;
  float acc[4][4] = {};
  for (int kb = 0; kb < KTOT; kb += 64) {
    #pragma unroll
    for (int p = 0; p < 2; p++) {
      int r = p * 16 + (tid >> 4);
      int c4 = (tid & 15) * 4;
      *(float4*)&Xs[r][c4] = *(const float4*)&X[(size_t)(n0 + r) * KTOT + kb + c4];
    }
    #pragma unroll
    for (int p = 0; p < 8; p++) {
      int c = (tid >> 4) + 16 * p;
      int kk0 = tid & 15;
      #pragma unroll
      for (int ii = 0; ii < 4; ii++)
        Wt[kk0 + 16 * ii][c] = W[(size_t)c * KTOT + kb + kk0 + 16 * ii];
    }
    __syncthreads();
    #pragma unroll
    for (int k4 = 0; k4 < 16; k4++) {
      float4 a4[4], b4[4];
      #pragma unroll
      for (int i = 0; i < 4; i++) a4[i] = *(const float4*)&Xs[4 * ty + i][4 * k4];
      #pragma unroll
      for (int k = 0; k < 4; k++) b4[k] = *(const float4*)&Wt[4 * k4 + k][4 * tx];
      #pragma unroll
      for (int k = 0; k < 4; k++) {
        #pragma unroll
        for (int i = 0; i < 4; i++) {
          float av = (k == 0) ? a4[i].x : (k == 1) ? a4[i].y : (k == 2) ? a4[i].z : a4[i].w;
          acc[i][0] = fmaf(av, b4[k].x, acc[i][0]);
          acc[i][1] = fmaf(av, b4[k].y, acc[i][1]);
          acc[i][2] = fmaf(av, b4[k].z, acc[i][2]);
          acc[i][3] = fmaf(av, b4[k].w, acc[i][3]);
        }
      }
    }
    __syncthreads();
  }
  const int c0 = 4 * tx;
  float4 bi = *(const float4*)&bias[c0];
  float4 gm = *(const float4*)&gam[c0];
  float4 be = *(const float4*)&bet[c0];
  #pragma unroll
  for (int i = 0; i < 4; i++) {
    int n = n0 + 4 * ty + i;
    float4 rs = *(const float4*)&Res[(size_t)n * DD + c0];
    float v0 = acc[i][0] + bi.x + rs.x;
    float v1 = acc[i][1] + bi.y + rs.y;
    float v2 = acc[i][2] + bi.z + rs.z;
    float v3 = acc[i][3] + bi.w + rs.w;
    float s1 = v0 + v1 + v2 + v3;
    float s2 = v0 * v0 + v1 * v1 + v2 * v2 + v3 * v3;
    // reduce across the 32 tx-lanes (xor<32 stays within the row's lane group)
    #pragma unroll
    for (int off = 16; off >= 1; off >>= 1) {
      s1 += __shfl_xor(s1, off);
      s2 += __shfl_xor(s2, off);
    }
    float mu = s1 * 0.0078125f;
    float var = s2 * 0.0078125f - mu * mu;
    float rstd = rsqrtf(var + 1e-5f);
    float4 o;
    o.x = (v0 - mu) * rstd * gm.x + be.x;
    o.y = (v1 - mu) * rstd * gm.y + be.y;
    o.z = (v2 - mu) * rstd * gm.z + be.z;
    o.w = (v3 - mu) * rstd * gm.w + be.w;
    *(float4*)&Y[(size_t)n * DD + c0] = o;
  }
}

// ---------------------------------------------------------------------------
// Transpose K slice of qkv into Kt[bh][d][s] for coalesced score reads.
__global__ void k_kt(const float* __restrict__ qkv, float* __restrict__ Kt) {
  const int st = blockIdx.x * 64;
  const int bh = blockIdx.y;
  const int b = bh >> 2, h = bh & 3;
  __shared__ float tile[64][33];
  const int tid = threadIdx.x;
  #pragma unroll
  for (int p = 0; p < 8; p++) {
    int sl = p * 8 + (tid >> 5);
    int d = tid & 31;
    tile[sl][d] = qkv[(size_t)(b * SS + st + sl) * 384 + 128 + h * 32 + d];
  }
  __syncthreads();
  int d = tid >> 3, s0 = (tid & 7) * 8;
  float* kt = Kt + ((size_t)bh * 32 + d) * 512 + st + s0;
  float4 v0, v1;
  v0.x = tile[s0 + 0][d]; v0.y = tile[s0 + 1][d]; v0.z = tile[s0 + 2][d]; v0.w = tile[s0 + 3][d];
  v1.x = tile[s0 + 4][d]; v1.y = tile[s0 + 5][d]; v1.z = tile[s0 + 6][d]; v1.w = tile[s0 + 7][d];
  *(float4*)kt = v0;
  *(float4*)(kt + 4) = v1;
}

// ---------------------------------------------------------------------------
// Fused attention for one (b,h), 64 q-rows per block. 4 waves, each wave owns
// 16 q-rows processed as 4 groups of 4. Scores: 4 rows x 8 ks per lane.
// Softmax: full-wave shuffle reduce. PV: P in per-wave LDS, V coalesced global.
__global__ __launch_bounds__(256) void k_attn(const float* __restrict__ qkv,
                                              const float* __restrict__ Kt,
                                              const int* __restrict__ sent,
                                              float* __restrict__ ctx) {
  const int qt = blockIdx.x;   // 0..7
  const int bh = blockIdx.y;   // 0..255
  const int b = bh >> 2, h = bh & 3;
  const int tid = threadIdx.x;
  const int w = tid >> 6;      // wave 0..3
  const int lane = tid & 63;
  __shared__ float Ps[4][4][520]; // [wave][row-in-group][ks]
  __shared__ float kb[512];       // key bias (0 or -1e9)
  for (int i = tid; i < 512; i += 256)
    kb[i] = (sent[b * SS + i] != 0) ? 0.f : -1e9f;
  __syncthreads();

  const float* ktp = Kt + (size_t)bh * 32 * 512 + lane;
  const int qbase = qt * 64 + w * 16;
  const float scale = 0.17677669529663687f; // 1/sqrt(32)

  for (int g = 0; g < 4; g++) {
    const int row0 = qbase + g * 4;
    float s_[4][8];
    #pragma unroll
    for (int r = 0; r < 4; r++)
      #pragma unroll
      for (int i = 0; i < 8; i++) s_[r][i] = 0.f;

    const float* qrow = qkv + (size_t)(b * SS + row0) * 384 + h * 32;
    #pragma unroll
    for (int dc = 0; dc < 8; dc++) {
      float4 q4[4];
      #pragma unroll
      for (int r = 0; r < 4; r++)
        q4[r] = *(const float4*)(qrow + (size_t)r * 384 + dc * 4);
      #pragma unroll
      for (int dd = 0; dd < 4; dd++) {
        int d = dc * 4 + dd;
        float kd[8];
        #pragma unroll
        for (int i = 0; i < 8; i++) kd[i] = ktp[(size_t)d * 512 + 64 * i];
        #pragma unroll
        for (int r = 0; r < 4; r++) {
          float qv = (dd == 0) ? q4[r].x : (dd == 1) ? q4[r].y : (dd == 2) ? q4[r].z : q4[r].w;
          #pragma unroll
          for (int i = 0; i < 8; i++) s_[r][i] = fmaf(qv, kd[i], s_[r][i]);
        }
      }
    }
    // softmax per row (scores for a row live across all 64 lanes x 8 regs)
    #pragma unroll
    for (int r = 0; r < 4; r++) {
      float m = -3.4e38f;
      #pragma unroll
      for (int i = 0; i < 8; i++) {
        s_[r][i] = s_[r][i] * scale + kb[lane + 64 * i];
        m = fmaxf(m, s_[r][i]);
      }
      #pragma unroll
      for (int off = 32; off >= 1; off >>= 1) m = fmaxf(m, __shfl_xor(m, off));
      float sum = 0.f;
      #pragma unroll
      for (int i = 0; i < 8; i++) { s_[r][i] = expf(s_[r][i] - m); sum += s_[r][i]; }
      #pragma unroll
      for (int off = 32; off >= 1; off >>= 1) sum += __shfl_xor(sum, off);
      float inv = 1.f / sum;
      #pragma unroll
      for (int i = 0; i < 8; i++) Ps[w][r][lane + 64 * i] = s_[r][i] * inv;
    }
    // PV: lane -> (d = lane&31, row-pair = lane>>5)
    const int dl = lane & 31, rh = lane >> 5;
    const float* vcol = qkv + (size_t)(b * SS) * 384 + 256 + h * 32 + dl;
    float acc0 = 0.f, acc1 = 0.f;
    #pragma unroll 4
    for (int ks = 0; ks < 512; ks += 4) {
      float4 pa = *(const float4*)&Ps[w][2 * rh][ks];
      float4 pb = *(const float4*)&Ps[w][2 * rh + 1][ks];
      float v0 = vcol[(size_t)(ks + 0) * 384];
      float v1 = vcol[(size_t)(ks + 1) * 384];
      float v2 = vcol[(size_t)(ks + 2) * 384];
      float v3 = vcol[(size_t)(ks + 3) * 384];
      acc0 = fmaf(pa.x, v0, acc0); acc0 = fmaf(pa.y, v1, acc0);
      acc0 = fmaf(pa.z, v2, acc0); acc0 = fmaf(pa.w, v3, acc0);
      acc1 = fmaf(pb.x, v0, acc1); acc1 = fmaf(pb.y, v1, acc1);
      acc1 = fmaf(pb.z, v2, acc1); acc1 = fmaf(pb.w, v3, acc1);
    }
    int row = row0 + 2 * rh;
    ctx[(size_t)(b * SS + row) * DD + h * 32 + dl] = acc0;
    ctx[(size_t)(b * SS + row + 1) * DD + h * 32 + dl] = acc1;
  }
}

// ---------------------------------------------------------------------------
// Emissions: em[n][t] = x[n][:] . Wtag[t][:] + btag[t]
__global__ void k_emis(const float* __restrict__ X, const float* __restrict__ Wtag,
                       const float* __restrict__ btag, float* __restrict__ em) {
  int idx = blockIdx.x * 256 + threadIdx.x;
  if (idx >= NN * TT) return;
  int n = idx / TT, t = idx - n * TT;
  const float* xr = X + (size_t)n * DD;
  const float* wr = Wtag + (size_t)t * DD;
  float acc = 0.f;
  #pragma unroll
  for (int k = 0; k < DD / 4; k++) {
    float4 x4 = *(const float4*)(xr + 4 * k);
    float4 w4 = *(const float4*)(wr + 4 * k);
    acc += x4.x * w4.x + x4.y * w4.y + x4.z * w4.z + x4.w * w4.w;
  }
  em[idx] = acc + btag[t];
}

// ---------------------------------------------------------------------------
// CRF: one wave per batch element. Lane j<9 carries fv[j]; 9 shfl broadcasts
// per step; uniform mask branch. Gold score parallelized over lanes.
__global__ void k_crf(const float* __restrict__ em, const int* __restrict__ sent,
                      const int* __restrict__ tags, const float* __restrict__ trans,
                      const float* __restrict__ start_t, const float* __restrict__ end_t,
                      float* __restrict__ part) {
  const int b = blockIdx.x;
  const int lane = threadIdx.x;        // 64 threads
  const int j = (lane < TT) ? lane : 0;
  float tr[TT];
  #pragma unroll
  for (int i = 0; i < TT; i++) tr[i] = trans[i * TT + j];
  const float* emb_ = em + (size_t)b * SS * TT;
  float fv = start_t[j] + emb_[j];
  for (int s = 1; s < SS; s++) {
    int tok = sent[b * SS + s];        // uniform across wave
    if (tok != 0) {
      float a[TT];
      #pragma unroll
      for (int i = 0; i < TT; i++) a[i] = __shfl(fv, i) + tr[i];
      float m = a[0];
      #pragma unroll
      for (int i = 1; i < TT; i++) m = fmaxf(m, a[i]);
      float sum = 0.f;
      #pragma unroll
      for (int i = 0; i < TT; i++) sum += expf(a[i] - m);
      fv = emb_[s * TT + j] + m + logf(sum);
    }
  }
  float aa[TT];
  #pragma unroll
  for (int i = 0; i < TT; i++) aa[i] = __shfl(fv, i) + end_t[i];
  float m2 = aa[0];
  #pragma unroll
  for (int i = 1; i < TT; i++) m2 = fmaxf(m2, aa[i]);
  float sum2 = 0.f;
  #pragma unroll
  for (int i = 0; i < TT; i++) sum2 += expf(aa[i] - m2);
  float fwd = m2 + logf(sum2);
  // gold path score, parallel over positions
  float p = 0.f;
  int cnt = 0;
  #pragma unroll
  for (int ii = 0; ii < 8; ii++) {
    int s = lane + 64 * ii;
    cnt += (sent[b * SS + s] != 0) ? 1 : 0;
    int s2 = s + 1;
    if (s2 < SS && sent[b * SS + s2] != 0) {
      int tp = tags[b * SS + s2 - 1];
      int tc = tags[b * SS + s2];
      p += trans[tp * TT + tc] + emb_[(size_t)s2 * TT + tc];
    }
  }
  #pragma unroll
  for (int off = 32; off >= 1; off >>= 1) {
    p += __shfl_xor(p, off);
    cnt += __shfl_xor(cnt, off);
  }
  if (lane == 0) {
    int t0 = tags[b * SS];
    float score = start_t[t0] + emb_[t0] + p;
    int lastt = tags[b * SS + cnt - 1];
    score += end_t[lastt];
    part[b] = fwd - score;
  }
}

__global__ void k_final(const float* __restrict__ part, float* __restrict__ out) {
  float v = part[threadIdx.x];
  #pragma unroll
  for (int off = 32; off >= 1; off >>= 1) v += __shfl_xor(v, off);
  if (threadIdx.x == 0) out[0] = v * (1.f / 64.f);
}

// ---------------------------------------------------------------------------
extern "C" void kernel_launch(void* const* d_in, const int* in_sizes, int n_in,
                              void* d_out, int out_size, void* d_ws, size_t ws_size,
                              hipStream_t stream) {
  const int*   sent  = (const int*)d_in[0];
  const int*   tags  = (const int*)d_in[1];
  const float* emb   = (const float*)d_in[2];
  const float* Wqkv  = (const float*)d_in[3];
  const float* bqkv  = (const float*)d_in[4];
  const float* Wo    = (const float*)d_in[5];
  const float* bo    = (const float*)d_in[6];
  const float* W1    = (const float*)d_in[7];
  const float* b1f   = (const float*)d_in[8];
  const float* W2    = (const float*)d_in[9];
  const float* b2f   = (const float*)d_in[10];
  const float* ln1g  = (const float*)d_in[11];
  const float* ln1b  = (const float*)d_in[12];
  const float* ln2g  = (const float*)d_in[13];
  const float* ln2b  = (const float*)d_in[14];
  const float* Wtag  = (const float*)d_in[15];
  const float* btag  = (const float*)d_in[16];
  const float* trans = (const float*)d_in[17];
  const float* st    = (const float*)d_in[18];
  const float* et    = (const float*)d_in[19];

  float* ws   = (float*)d_ws;
  float* xA   = ws + OFF_X;
  float* xB   = ws + OFF_Y;
  float* qkv  = ws + OFF_QKV;
  float* ff   = ws + OFF_QKV;   // reuse: FF hidden fits in qkv region
  float* ctx  = ws + OFF_CTX;
  float* Kt   = ws + OFF_KT;
  float* em   = ws + OFF_EM;
  float* part = ws + OFF_PART;
  float* out  = (float*)d_out;

  k_embed<<<NN, DD, 0, stream>>>(sent, emb, xA);

  for (int l = 0; l < LL; l++) {
    k_gemm<128, false><<<dim3(NN / 64, 6), 256, 0, stream>>>(
        xA, Wqkv + (size_t)l * 3 * DD * DD, bqkv + l * 3 * DD, qkv, 3 * DD);
    k_kt<<<dim3(8, BB * HH), 256, 0, stream>>>(qkv, Kt);
    k_attn<<<dim3(8, BB * HH), 256, 0, stream>>>(qkv, Kt, sent, ctx);
    k_gemm_ln<128><<<dim3(NN / 32), 256, 0, stream>>>(
        ctx, Wo + (size_t)l * DD * DD, bo + l * DD, xA, ln1g + l * DD, ln1b + l * DD, xB);
    k_gemm<128, true><<<dim3(NN / 64, 4), 256, 0, stream>>>(
        xB, W1 + (size_t)l * DFFc * DD, b1f + l * DFFc, ff, DFFc);
    k_gemm_ln<256><<<dim3(NN / 32), 256, 0, stream>>>(
        ff, W2 + (size_t)l * DD * DFFc, b2f + l * DD, xB, ln2g + l * DD, ln2b + l * DD, xA);
  }

  k_emis<<<(NN * TT + 255) / 256, 256, 0, stream>>>(xA, Wtag, btag, em);
  k_crf<<<BB, 64, 0, stream>>>(em, sent, tags, trans, st, et, part);
  k_final<<<1, 64, 0, stream>>>(part, out);
}

// Round 2
// 1933.622 us; speedup vs baseline: 1.3512x; 1.3512x over previous
//
#include <hip/hip_runtime.h>

// Problem constants
#define BB   64
#define SS   512
#define DD   128
#define DFFc 256
#define HH   4
#define TT   9
#define LL   2
#define HDc  32
#define NN   (BB*SS)   // 32768 tokens

// Workspace layout (float offsets)
#define OFF_X    0
#define OFF_Y    (NN*DD)
#define OFF_QKV  (2*NN*DD)          // 3*NN*DD floats; reused for FF hidden (NN*DFFc = 2*NN*DD)
#define OFF_CTX  (5*NN*DD)
#define OFF_KT   (6*NN*DD)
#define OFF_EM   (7*NN*DD)
#define OFF_PART (7*NN*DD + NN*TT)

// ---------------------------------------------------------------------------
// Embedding + sinusoidal positional encoding.
__global__ void k_embed(const int* __restrict__ sent, const float* __restrict__ emb,
                        float* __restrict__ x) {
  int n = blockIdx.x;
  int d = threadIdx.x;
  int tok = sent[n];
  int s = n & (SS - 1);
  float e = (tok != 0) ? emb[(size_t)tok * DD + d] : 0.f;
  int i = d >> 1;
  float dv = expf((float)(2 * i) * (-9.210340371976184f / (float)DD)); // -ln(10000)/D
  float ang = (float)s * dv;
  float pe = (d & 1) ? cosf(ang) : sinf(ang);
  x[(size_t)n * DD + d] = e + pe;
}

// ---------------------------------------------------------------------------
// Generic tiled GEMM: Y[n][c] = act( sum_k X[n][k]*W[c][k] + bias[c] )
template <int KTOT, bool RELU>
__global__ __launch_bounds__(256) void k_gemm(const float* __restrict__ X,
                                              const float* __restrict__ W,
                                              const float* __restrict__ bias,
                                              float* __restrict__ Y, int ldY) {
  __shared__ float Xs[64][68];
  __shared__ float Wt[64][68];
  const int tid = threadIdx.x;
  const int tx = tid & 15, ty = tid >> 4;
  const int n0 = blockIdx.x * 64, c0g = blockIdx.y * 64;
  float acc[4][4] = {};
  for (int kb = 0; kb < KTOT; kb += 64) {
    #pragma unroll
    for (int p = 0; p < 4; p++) {
      int r = p * 16 + (tid >> 4);
      int c4 = (tid & 15) * 4;
      *(float4*)&Xs[r][c4] = *(const float4*)&X[(size_t)(n0 + r) * KTOT + kb + c4];
    }
    #pragma unroll
    for (int p = 0; p < 4; p++) {
      int c = (tid >> 4) + 16 * p;
      int kk0 = tid & 15;
      #pragma unroll
      for (int ii = 0; ii < 4; ii++)
        Wt[kk0 + 16 * ii][c] = W[(size_t)(c0g + c) * KTOT + kb + kk0 + 16 * ii];
    }
    __syncthreads();
    #pragma unroll
    for (int k4 = 0; k4 < 16; k4++) {
      float4 a4[4], b4[4];
      #pragma unroll
      for (int i = 0; i < 4; i++) a4[i] = *(const float4*)&Xs[4 * ty + i][4 * k4];
      #pragma unroll
      for (int k = 0; k < 4; k++) b4[k] = *(const float4*)&Wt[4 * k4 + k][4 * tx];
      #pragma unroll
      for (int k = 0; k < 4; k++) {
        #pragma unroll
        for (int i = 0; i < 4; i++) {
          float av = (k == 0) ? a4[i].x : (k == 1) ? a4[i].y : (k == 2) ? a4[i].z : a4[i].w;
          acc[i][0] = fmaf(av, b4[k].x, acc[i][0]);
          acc[i][1] = fmaf(av, b4[k].y, acc[i][1]);
          acc[i][2] = fmaf(av, b4[k].z, acc[i][2]);
          acc[i][3] = fmaf(av, b4[k].w, acc[i][3]);
        }
      }
    }
    __syncthreads();
  }
  float4 bi = *(const float4*)&bias[c0g + 4 * tx];
  #pragma unroll
  for (int i = 0; i < 4; i++) {
    float4 o;
    o.x = acc[i][0] + bi.x; o.y = acc[i][1] + bi.y;
    o.z = acc[i][2] + bi.z; o.w = acc[i][3] + bi.w;
    if (RELU) {
      o.x = fmaxf(o.x, 0.f); o.y = fmaxf(o.y, 0.f);
      o.z = fmaxf(o.z, 0.f); o.w = fmaxf(o.w, 0.f);
    }
    *(float4*)&Y[(size_t)(n0 + 4 * ty + i) * ldY + c0g + 4 * tx] = o;
  }
}

// ---------------------------------------------------------------------------
// GEMM + bias + residual + LayerNorm fused. Block = 32 rows x full 128 cols.
template <int KTOT>
__global__ __launch_bounds__(256) void k_gemm_ln(const float* __restrict__ X,
                                                 const float* __restrict__ W,
                                                 const float* __restrict__ bias,
                                                 const float* __restrict__ Res,
                                                 const float* __restrict__ gam,
                                                 const float* __restrict__ bet,
                                                 float* __restrict__ Y) {
  __shared__ float Xs[32][68];
  __shared__ float Wt[64][132];
  const int tid = threadIdx.x;
  const int tx = tid & 31, ty = tid >> 5;
  const int n0 = blockIdx.x * 32;
  float acc[4][4] = {};
  for (int kb = 0; kb < KTOT; kb += 64) {
    #pragma unroll
    for (int p = 0; p < 2; p++) {
      int r = p * 16 + (tid >> 4);
      int c4 = (tid & 15) * 4;
      *(float4*)&Xs[r][c4] = *(const float4*)&X[(size_t)(n0 + r) * KTOT + kb + c4];
    }
    #pragma unroll
    for (int p = 0; p < 8; p++) {
      int c = (tid >> 4) + 16 * p;
      int kk0 = tid & 15;
      #pragma unroll
      for (int ii = 0; ii < 4; ii++)
        Wt[kk0 + 16 * ii][c] = W[(size_t)c * KTOT + kb + kk0 + 16 * ii];
    }
    __syncthreads();
    #pragma unroll
    for (int k4 = 0; k4 < 16; k4++) {
      float4 a4[4], b4[4];
      #pragma unroll
      for (int i = 0; i < 4; i++) a4[i] = *(const float4*)&Xs[4 * ty + i][4 * k4];
      #pragma unroll
      for (int k = 0; k < 4; k++) b4[k] = *(const float4*)&Wt[4 * k4 + k][4 * tx];
      #pragma unroll
      for (int k = 0; k < 4; k++) {
        #pragma unroll
        for (int i = 0; i < 4; i++) {
          float av = (k == 0) ? a4[i].x : (k == 1) ? a4[i].y : (k == 2) ? a4[i].z : a4[i].w;
          acc[i][0] = fmaf(av, b4[k].x, acc[i][0]);
          acc[i][1] = fmaf(av, b4[k].y, acc[i][1]);
          acc[i][2] = fmaf(av, b4[k].z, acc[i][2]);
          acc[i][3] = fmaf(av, b4[k].w, acc[i][3]);
        }
      }
    }
    __syncthreads();
  }
  const int c0 = 4 * tx;
  float4 bi = *(const float4*)&bias[c0];
  float4 gm = *(const float4*)&gam[c0];
  float4 be = *(const float4*)&bet[c0];
  #pragma unroll
  for (int i = 0; i < 4; i++) {
    int n = n0 + 4 * ty + i;
    float4 rs = *(const float4*)&Res[(size_t)n * DD + c0];
    float v0 = acc[i][0] + bi.x + rs.x;
    float v1 = acc[i][1] + bi.y + rs.y;
    float v2 = acc[i][2] + bi.z + rs.z;
    float v3 = acc[i][3] + bi.w + rs.w;
    float s1 = v0 + v1 + v2 + v3;
    float s2 = v0 * v0 + v1 * v1 + v2 * v2 + v3 * v3;
    #pragma unroll
    for (int off = 16; off >= 1; off >>= 1) {
      s1 += __shfl_xor(s1, off);
      s2 += __shfl_xor(s2, off);
    }
    float mu = s1 * 0.0078125f;
    float var = s2 * 0.0078125f - mu * mu;
    float rstd = rsqrtf(var + 1e-5f);
    float4 o;
    o.x = (v0 - mu) * rstd * gm.x + be.x;
    o.y = (v1 - mu) * rstd * gm.y + be.y;
    o.z = (v2 - mu) * rstd * gm.z + be.z;
    o.w = (v3 - mu) * rstd * gm.w + be.w;
    *(float4*)&Y[(size_t)n * DD + c0] = o;
  }
}

// ---------------------------------------------------------------------------
// Transpose K slice of qkv into Kt[bh][d][s].
__global__ void k_kt(const float* __restrict__ qkv, float* __restrict__ Kt) {
  const int st = blockIdx.x * 64;
  const int bh = blockIdx.y;
  const int b = bh >> 2, h = bh & 3;
  __shared__ float tile[64][33];
  const int tid = threadIdx.x;
  #pragma unroll
  for (int p = 0; p < 8; p++) {
    int sl = p * 8 + (tid >> 5);
    int d = tid & 31;
    tile[sl][d] = qkv[(size_t)(b * SS + st + sl) * 384 + 128 + h * 32 + d];
  }
  __syncthreads();
  int d = tid >> 3, s0 = (tid & 7) * 8;
  float* kt = Kt + ((size_t)bh * 32 + d) * 512 + st + s0;
  float4 v0, v1;
  v0.x = tile[s0 + 0][d]; v0.y = tile[s0 + 1][d]; v0.z = tile[s0 + 2][d]; v0.w = tile[s0 + 3][d];
  v1.x = tile[s0 + 4][d]; v1.y = tile[s0 + 5][d]; v1.z = tile[s0 + 6][d]; v1.w = tile[s0 + 7][d];
  *(float4*)kt = v0;
  *(float4*)(kt + 4) = v1;
}

// ---------------------------------------------------------------------------
// Fused attention for one (b,h), 64 q-rows per block, 4 waves x 16 rows.
// Score layout: lane owns ks = {4*lane..4*lane+3} and {256+4*lane..+3} (float4 K loads).
// PV layout: lane = (ks-stream rh = lane>>3, d-quad dl = lane&7); P via ds_read_b128,
// V via coalesced float4; xor-reduce over the 8 ks-streams.
__global__ __launch_bounds__(256, 4) void k_attn(const float* __restrict__ qkv,
                                                 const float* __restrict__ Kt,
                                                 const int* __restrict__ sent,
                                                 float* __restrict__ ctx) {
  const int qt = blockIdx.x;   // 0..7
  const int bh = blockIdx.y;   // 0..255
  const int b = bh >> 2, h = bh & 3;
  const int tid = threadIdx.x;
  const int w = tid >> 6;
  const int lane = tid & 63;
  __shared__ float Ps[4][4][512];  // [wave][row-in-group][ks] = 32 KB

  // key-bias in registers: ks = 4*lane + {0..3} and 256 + 4*lane + {0..3}
  int4 t0 = *(const int4*)&sent[b * SS + 4 * lane];
  int4 t1 = *(const int4*)&sent[b * SS + 256 + 4 * lane];
  float4 kb0, kb1;
  kb0.x = t0.x ? 0.f : -1e9f; kb0.y = t0.y ? 0.f : -1e9f;
  kb0.z = t0.z ? 0.f : -1e9f; kb0.w = t0.w ? 0.f : -1e9f;
  kb1.x = t1.x ? 0.f : -1e9f; kb1.y = t1.y ? 0.f : -1e9f;
  kb1.z = t1.z ? 0.f : -1e9f; kb1.w = t1.w ? 0.f : -1e9f;

  const int qbase = qt * 64 + w * 16;
  const float scale = 0.17677669529663687f; // 1/sqrt(32)
  const float* ktbase = Kt + (size_t)bh * 32 * 512 + 4 * lane;

  for (int g = 0; g < 4; g++) {
    const int row0 = qbase + g * 4;
    float4 s0[4], s1[4];
    #pragma unroll
    for (int r = 0; r < 4; r++) {
      s0[r].x = s0[r].y = s0[r].z = s0[r].w = 0.f;
      s1[r].x = s1[r].y = s1[r].z = s1[r].w = 0.f;
    }
    const float* qrow = qkv + (size_t)(b * SS + row0) * 384 + h * 32;
    #pragma unroll
    for (int dc = 0; dc < 8; dc++) {
      float4 q4[4];
      #pragma unroll
      for (int r = 0; r < 4; r++)
        q4[r] = *(const float4*)(qrow + (size_t)r * 384 + dc * 4);
      #pragma unroll
      for (int dd = 0; dd < 4; dd++) {
        const float* kp = ktbase + (size_t)(dc * 4 + dd) * 512;
        float4 k0 = *(const float4*)kp;
        float4 k1 = *(const float4*)(kp + 256);
        #pragma unroll
        for (int r = 0; r < 4; r++) {
          float qv = (dd == 0) ? q4[r].x : (dd == 1) ? q4[r].y : (dd == 2) ? q4[r].z : q4[r].w;
          s0[r].x = fmaf(qv, k0.x, s0[r].x); s0[r].y = fmaf(qv, k0.y, s0[r].y);
          s0[r].z = fmaf(qv, k0.z, s0[r].z); s0[r].w = fmaf(qv, k0.w, s0[r].w);
          s1[r].x = fmaf(qv, k1.x, s1[r].x); s1[r].y = fmaf(qv, k1.y, s1[r].y);
          s1[r].z = fmaf(qv, k1.z, s1[r].z); s1[r].w = fmaf(qv, k1.w, s1[r].w);
        }
      }
    }
    // softmax per row
    #pragma unroll
    for (int r = 0; r < 4; r++) {
      float4 a = s0[r], c = s1[r];
      a.x = fmaf(a.x, scale, kb0.x); a.y = fmaf(a.y, scale, kb0.y);
      a.z = fmaf(a.z, scale, kb0.z); a.w = fmaf(a.w, scale, kb0.w);
      c.x = fmaf(c.x, scale, kb1.x); c.y = fmaf(c.y, scale, kb1.y);
      c.z = fmaf(c.z, scale, kb1.z); c.w = fmaf(c.w, scale, kb1.w);
      float m = fmaxf(fmaxf(fmaxf(a.x, a.y), fmaxf(a.z, a.w)),
                      fmaxf(fmaxf(c.x, c.y), fmaxf(c.z, c.w)));
      #pragma unroll
      for (int off = 32; off >= 1; off >>= 1) m = fmaxf(m, __shfl_xor(m, off));
      a.x = expf(a.x - m); a.y = expf(a.y - m); a.z = expf(a.z - m); a.w = expf(a.w - m);
      c.x = expf(c.x - m); c.y = expf(c.y - m); c.z = expf(c.z - m); c.w = expf(c.w - m);
      float sum = a.x + a.y + a.z + a.w + c.x + c.y + c.z + c.w;
      #pragma unroll
      for (int off = 32; off >= 1; off >>= 1) sum += __shfl_xor(sum, off);
      float inv = 1.f / sum;
      a.x *= inv; a.y *= inv; a.z *= inv; a.w *= inv;
      c.x *= inv; c.y *= inv; c.z *= inv; c.w *= inv;
      *(float4*)&Ps[w][r][4 * lane] = a;
      *(float4*)&Ps[w][r][256 + 4 * lane] = c;
    }
    // PV
    const int dl = lane & 7, rh = lane >> 3;
    const float* vbase = qkv + (size_t)(b * SS) * 384 + 256 + h * 32 + 4 * dl;
    float4 acc[4];
    #pragma unroll
    for (int r = 0; r < 4; r++) acc[r].x = acc[r].y = acc[r].z = acc[r].w = 0.f;
    #pragma unroll 4
    for (int t = 0; t < 16; t++) {
      int ks = 4 * rh + 32 * t;
      float4 p[4];
      #pragma unroll
      for (int r = 0; r < 4; r++) p[r] = *(const float4*)&Ps[w][r][ks];
      float4 v[4];
      #pragma unroll
      for (int kk = 0; kk < 4; kk++) v[kk] = *(const float4*)(vbase + (size_t)(ks + kk) * 384);
      #pragma unroll
      for (int r = 0; r < 4; r++) {
        acc[r].x = fmaf(p[r].x, v[0].x, acc[r].x);
        acc[r].y = fmaf(p[r].x, v[0].y, acc[r].y);
        acc[r].z = fmaf(p[r].x, v[0].z, acc[r].z);
        acc[r].w = fmaf(p[r].x, v[0].w, acc[r].w);
        acc[r].x = fmaf(p[r].y, v[1].x, acc[r].x);
        acc[r].y = fmaf(p[r].y, v[1].y, acc[r].y);
        acc[r].z = fmaf(p[r].y, v[1].z, acc[r].z);
        acc[r].w = fmaf(p[r].y, v[1].w, acc[r].w);
        acc[r].x = fmaf(p[r].z, v[2].x, acc[r].x);
        acc[r].y = fmaf(p[r].z, v[2].y, acc[r].y);
        acc[r].z = fmaf(p[r].z, v[2].z, acc[r].z);
        acc[r].w = fmaf(p[r].z, v[2].w, acc[r].w);
        acc[r].x = fmaf(p[r].w, v[3].x, acc[r].x);
        acc[r].y = fmaf(p[r].w, v[3].y, acc[r].y);
        acc[r].z = fmaf(p[r].w, v[3].z, acc[r].z);
        acc[r].w = fmaf(p[r].w, v[3].w, acc[r].w);
      }
    }
    // reduce across the 8 ks-streams
    #pragma unroll
    for (int off = 8; off <= 32; off <<= 1) {
      #pragma unroll
      for (int r = 0; r < 4; r++) {
        acc[r].x += __shfl_xor(acc[r].x, off);
        acc[r].y += __shfl_xor(acc[r].y, off);
        acc[r].z += __shfl_xor(acc[r].z, off);
        acc[r].w += __shfl_xor(acc[r].w, off);
      }
    }
    if (lane < 32) {
      int r = lane >> 3, d2 = lane & 7;
      float4 o;
      o.x = (r == 0) ? acc[0].x : (r == 1) ? acc[1].x : (r == 2) ? acc[2].x : acc[3].x;
      o.y = (r == 0) ? acc[0].y : (r == 1) ? acc[1].y : (r == 2) ? acc[2].y : acc[3].y;
      o.z = (r == 0) ? acc[0].z : (r == 1) ? acc[1].z : (r == 2) ? acc[2].z : acc[3].z;
      o.w = (r == 0) ? acc[0].w : (r == 1) ? acc[1].w : (r == 2) ? acc[2].w : acc[3].w;
      *(float4*)&ctx[(size_t)(b * SS + row0 + r) * DD + h * 32 + 4 * d2] = o;
    }
  }
}

// ---------------------------------------------------------------------------
// Emissions: em[n][t] = x[n][:] . Wtag[t][:] + btag[t]
__global__ void k_emis(const float* __restrict__ X, const float* __restrict__ Wtag,
                       const float* __restrict__ btag, float* __restrict__ em) {
  int idx = blockIdx.x * 256 + threadIdx.x;
  if (idx >= NN * TT) return;
  int n = idx / TT, t = idx - n * TT;
  const float* xr = X + (size_t)n * DD;
  const float* wr = Wtag + (size_t)t * DD;
  float acc = 0.f;
  #pragma unroll
  for (int k = 0; k < DD / 4; k++) {
    float4 x4 = *(const float4*)(xr + 4 * k);
    float4 w4 = *(const float4*)(wr + 4 * k);
    acc += x4.x * w4.x + x4.y * w4.y + x4.z * w4.z + x4.w * w4.w;
  }
  em[idx] = acc + btag[t];
}

// ---------------------------------------------------------------------------
// CRF: one wave per batch element.
__global__ void k_crf(const float* __restrict__ em, const int* __restrict__ sent,
                      const int* __restrict__ tags, const float* __restrict__ trans,
                      const float* __restrict__ start_t, const float* __restrict__ end_t,
                      float* __restrict__ part) {
  const int b = blockIdx.x;
  const int lane = threadIdx.x;
  const int j = (lane < TT) ? lane : 0;
  float tr[TT];
  #pragma unroll
  for (int i = 0; i < TT; i++) tr[i] = trans[i * TT + j];
  const float* emb_ = em + (size_t)b * SS * TT;
  float fv = start_t[j] + emb_[j];
  for (int s = 1; s < SS; s++) {
    int tok = sent[b * SS + s];
    if (tok != 0) {
      float a[TT];
      #pragma unroll
      for (int i = 0; i < TT; i++) a[i] = __shfl(fv, i) + tr[i];
      float m = a[0];
      #pragma unroll
      for (int i = 1; i < TT; i++) m = fmaxf(m, a[i]);
      float sum = 0.f;
      #pragma unroll
      for (int i = 0; i < TT; i++) sum += expf(a[i] - m);
      fv = emb_[s * TT + j] + m + logf(sum);
    }
  }
  float aa[TT];
  #pragma unroll
  for (int i = 0; i < TT; i++) aa[i] = __shfl(fv, i) + end_t[i];
  float m2 = aa[0];
  #pragma unroll
  for (int i = 1; i < TT; i++) m2 = fmaxf(m2, aa[i]);
  float sum2 = 0.f;
  #pragma unroll
  for (int i = 0; i < TT; i++) sum2 += expf(aa[i] - m2);
  float fwd = m2 + logf(sum2);
  float p = 0.f;
  int cnt = 0;
  #pragma unroll
  for (int ii = 0; ii < 8; ii++) {
    int s = lane + 64 * ii;
    cnt += (sent[b * SS + s] != 0) ? 1 : 0;
    int s2 = s + 1;
    if (s2 < SS && sent[b * SS + s2] != 0) {
      int tp = tags[b * SS + s2 - 1];
      int tc = tags[b * SS + s2];
      p += trans[tp * TT + tc] + emb_[(size_t)s2 * TT + tc];
    }
  }
  #pragma unroll
  for (int off = 32; off >= 1; off >>= 1) {
    p += __shfl_xor(p, off);
    cnt += __shfl_xor(cnt, off);
  }
  if (lane == 0) {
    int t0 = tags[b * SS];
    float score = start_t[t0] + emb_[t0] + p;
    int lastt = tags[b * SS + cnt - 1];
    score += end_t[lastt];
    part[b] = fwd - score;
  }
}

__global__ void k_final(const float* __restrict__ part, float* __restrict__ out) {
  float v = part[threadIdx.x];
  #pragma unroll
  for (int off = 32; off >= 1; off >>= 1) v += __shfl_xor(v, off);
  if (threadIdx.x == 0) out[0] = v * (1.f / 64.f);
}

// ---------------------------------------------------------------------------
extern "C" void kernel_launch(void* const* d_in, const int* in_sizes, int n_in,
                              void* d_out, int out_size, void* d_ws, size_t ws_size,
                              hipStream_t stream) {
  const int*   sent  = (const int*)d_in[0];
  const int*   tags  = (const int*)d_in[1];
  const float* emb   = (const float*)d_in[2];
  const float* Wqkv  = (const float*)d_in[3];
  const float* bqkv  = (const float*)d_in[4];
  const float* Wo    = (const float*)d_in[5];
  const float* bo    = (const float*)d_in[6];
  const float* W1    = (const float*)d_in[7];
  const float* b1f   = (const float*)d_in[8];
  const float* W2    = (const float*)d_in[9];
  const float* b2f   = (const float*)d_in[10];
  const float* ln1g  = (const float*)d_in[11];
  const float* ln1b  = (const float*)d_in[12];
  const float* ln2g  = (const float*)d_in[13];
  const float* ln2b  = (const float*)d_in[14];
  const float* Wtag  = (const float*)d_in[15];
  const float* btag  = (const float*)d_in[16];
  const float* trans = (const float*)d_in[17];
  const float* st    = (const float*)d_in[18];
  const float* et    = (const float*)d_in[19];

  float* ws   = (float*)d_ws;
  float* xA   = ws + OFF_X;
  float* xB   = ws + OFF_Y;
  float* qkv  = ws + OFF_QKV;
  float* ff   = ws + OFF_QKV;
  float* ctx  = ws + OFF_CTX;
  float* Kt   = ws + OFF_KT;
  float* em   = ws + OFF_EM;
  float* part = ws + OFF_PART;
  float* out  = (float*)d_out;

  k_embed<<<NN, DD, 0, stream>>>(sent, emb, xA);

  for (int l = 0; l < LL; l++) {
    k_gemm<128, false><<<dim3(NN / 64, 6), 256, 0, stream>>>(
        xA, Wqkv + (size_t)l * 3 * DD * DD, bqkv + l * 3 * DD, qkv, 3 * DD);
    k_kt<<<dim3(8, BB * HH), 256, 0, stream>>>(qkv, Kt);
    k_attn<<<dim3(8, BB * HH), 256, 0, stream>>>(qkv, Kt, sent, ctx);
    k_gemm_ln<128><<<dim3(NN / 32), 256, 0, stream>>>(
        ctx, Wo + (size_t)l * DD * DD, bo + l * DD, xA, ln1g + l * DD, ln1b + l * DD, xB);
    k_gemm<128, true><<<dim3(NN / 64, 4), 256, 0, stream>>>(
        xB, W1 + (size_t)l * DFFc * DD, b1f + l * DFFc, ff, DFFc);
    k_gemm_ln<256><<<dim3(NN / 32), 256, 0, stream>>>(
        ff, W2 + (size_t)l * DD * DFFc, b2f + l * DD, xB, ln2g + l * DD, ln2b + l * DD, xA);
  }

  k_emis<<<(NN * TT + 255) / 256, 256, 0, stream>>>(xA, Wtag, btag, em);
  k_crf<<<BB, 64, 0, stream>>>(em, sent, tags, trans, st, et, part);
  k_final<<<1, 64, 0, stream>>>(part, out);
}

// Round 3
// 1902.960 us; speedup vs baseline: 1.3730x; 1.0161x over previous
//
#include <hip/hip_runtime.h>

// Problem constants
#define BB   64
#define SS   512
#define DD   128
#define DFFc 256
#define HH   4
#define TT   9
#define LL   2
#define HDc  32
#define NN   (BB*SS)   // 32768 tokens

// Workspace layout (float offsets)
#define OFF_X    0
#define OFF_Y    (NN*DD)
#define OFF_QKV  (2*NN*DD)          // 3*NN*DD floats; reused for FF hidden
#define OFF_CTX  (5*NN*DD)
#define OFF_KT   (6*NN*DD)
#define OFF_EM   (7*NN*DD)
#define OFF_PART (7*NN*DD + NN*TT)

// ---------------------------------------------------------------------------
__global__ void k_embed(const int* __restrict__ sent, const float* __restrict__ emb,
                        float* __restrict__ x) {
  int n = blockIdx.x;
  int d = threadIdx.x;
  int tok = sent[n];
  int s = n & (SS - 1);
  float e = (tok != 0) ? emb[(size_t)tok * DD + d] : 0.f;
  int i = d >> 1;
  float dv = expf((float)(2 * i) * (-9.210340371976184f / (float)DD));
  float ang = (float)s * dv;
  float pe = (d & 1) ? cosf(ang) : sinf(ang);
  x[(size_t)n * DD + d] = e + pe;
}

// ---------------------------------------------------------------------------
template <int KTOT, bool RELU>
__global__ __launch_bounds__(256) void k_gemm(const float* __restrict__ X,
                                              const float* __restrict__ W,
                                              const float* __restrict__ bias,
                                              float* __restrict__ Y, int ldY) {
  __shared__ float Xs[64][68];
  __shared__ float Wt[64][68];
  const int tid = threadIdx.x;
  const int tx = tid & 15, ty = tid >> 4;
  const int n0 = blockIdx.x * 64, c0g = blockIdx.y * 64;
  float acc[4][4] = {};
  for (int kb = 0; kb < KTOT; kb += 64) {
    #pragma unroll
    for (int p = 0; p < 4; p++) {
      int r = p * 16 + (tid >> 4);
      int c4 = (tid & 15) * 4;
      *(float4*)&Xs[r][c4] = *(const float4*)&X[(size_t)(n0 + r) * KTOT + kb + c4];
    }
    #pragma unroll
    for (int p = 0; p < 4; p++) {
      int c = (tid >> 4) + 16 * p;
      int kk0 = tid & 15;
      #pragma unroll
      for (int ii = 0; ii < 4; ii++)
        Wt[kk0 + 16 * ii][c] = W[(size_t)(c0g + c) * KTOT + kb + kk0 + 16 * ii];
    }
    __syncthreads();
    #pragma unroll
    for (int k4 = 0; k4 < 16; k4++) {
      float4 a4[4], b4[4];
      #pragma unroll
      for (int i = 0; i < 4; i++) a4[i] = *(const float4*)&Xs[4 * ty + i][4 * k4];
      #pragma unroll
      for (int k = 0; k < 4; k++) b4[k] = *(const float4*)&Wt[4 * k4 + k][4 * tx];
      #pragma unroll
      for (int k = 0; k < 4; k++) {
        #pragma unroll
        for (int i = 0; i < 4; i++) {
          float av = (k == 0) ? a4[i].x : (k == 1) ? a4[i].y : (k == 2) ? a4[i].z : a4[i].w;
          acc[i][0] = fmaf(av, b4[k].x, acc[i][0]);
          acc[i][1] = fmaf(av, b4[k].y, acc[i][1]);
          acc[i][2] = fmaf(av, b4[k].z, acc[i][2]);
          acc[i][3] = fmaf(av, b4[k].w, acc[i][3]);
        }
      }
    }
    __syncthreads();
  }
  float4 bi = *(const float4*)&bias[c0g + 4 * tx];
  #pragma unroll
  for (int i = 0; i < 4; i++) {
    float4 o;
    o.x = acc[i][0] + bi.x; o.y = acc[i][1] + bi.y;
    o.z = acc[i][2] + bi.z; o.w = acc[i][3] + bi.w;
    if (RELU) {
      o.x = fmaxf(o.x, 0.f); o.y = fmaxf(o.y, 0.f);
      o.z = fmaxf(o.z, 0.f); o.w = fmaxf(o.w, 0.f);
    }
    *(float4*)&Y[(size_t)(n0 + 4 * ty + i) * ldY + c0g + 4 * tx] = o;
  }
}

// ---------------------------------------------------------------------------
template <int KTOT>
__global__ __launch_bounds__(256) void k_gemm_ln(const float* __restrict__ X,
                                                 const float* __restrict__ W,
                                                 const float* __restrict__ bias,
                                                 const float* __restrict__ Res,
                                                 const float* __restrict__ gam,
                                                 const float* __restrict__ bet,
                                                 float* __restrict__ Y) {
  __shared__ float Xs[32][68];
  __shared__ float Wt[64][132];
  const int tid = threadIdx.x;
  const int tx = tid & 31, ty = tid >> 5;
  const int n0 = blockIdx.x * 32;
  float acc[4][4] = {};
  for (int kb = 0; kb < KTOT; kb += 64) {
    #pragma unroll
    for (int p = 0; p < 2; p++) {
      int r = p * 16 + (tid >> 4);
      int c4 = (tid & 15) * 4;
      *(float4*)&Xs[r][c4] = *(const float4*)&X[(size_t)(n0 + r) * KTOT + kb + c4];
    }
    #pragma unroll
    for (int p = 0; p < 8; p++) {
      int c = (tid >> 4) + 16 * p;
      int kk0 = tid & 15;
      #pragma unroll
      for (int ii = 0; ii < 4; ii++)
        Wt[kk0 + 16 * ii][c] = W[(size_t)c * KTOT + kb + kk0 + 16 * ii];
    }
    __syncthreads();
    #pragma unroll
    for (int k4 = 0; k4 < 16; k4++) {
      float4 a4[4], b4[4];
      #pragma unroll
      for (int i = 0; i < 4; i++) a4[i] = *(const float4*)&Xs[4 * ty + i][4 * k4];
      #pragma unroll
      for (int k = 0; k < 4; k++) b4[k] = *(const float4*)&Wt[4 * k4 + k][4 * tx];
      #pragma unroll
      for (int k = 0; k < 4; k++) {
        #pragma unroll
        for (int i = 0; i < 4; i++) {
          float av = (k == 0) ? a4[i].x : (k == 1) ? a4[i].y : (k == 2) ? a4[i].z : a4[i].w;
          acc[i][0] = fmaf(av, b4[k].x, acc[i][0]);
          acc[i][1] = fmaf(av, b4[k].y, acc[i][1]);
          acc[i][2] = fmaf(av, b4[k].z, acc[i][2]);
          acc[i][3] = fmaf(av, b4[k].w, acc[i][3]);
        }
      }
    }
    __syncthreads();
  }
  const int c0 = 4 * tx;
  float4 bi = *(const float4*)&bias[c0];
  float4 gm = *(const float4*)&gam[c0];
  float4 be = *(const float4*)&bet[c0];
  #pragma unroll
  for (int i = 0; i < 4; i++) {
    int n = n0 + 4 * ty + i;
    float4 rs = *(const float4*)&Res[(size_t)n * DD + c0];
    float v0 = acc[i][0] + bi.x + rs.x;
    float v1 = acc[i][1] + bi.y + rs.y;
    float v2 = acc[i][2] + bi.z + rs.z;
    float v3 = acc[i][3] + bi.w + rs.w;
    float s1 = v0 + v1 + v2 + v3;
    float s2 = v0 * v0 + v1 * v1 + v2 * v2 + v3 * v3;
    #pragma unroll
    for (int off = 16; off >= 1; off >>= 1) {
      s1 += __shfl_xor(s1, off);
      s2 += __shfl_xor(s2, off);
    }
    float mu = s1 * 0.0078125f;
    float var = s2 * 0.0078125f - mu * mu;
    float rstd = rsqrtf(var + 1e-5f);
    float4 o;
    o.x = (v0 - mu) * rstd * gm.x + be.x;
    o.y = (v1 - mu) * rstd * gm.y + be.y;
    o.z = (v2 - mu) * rstd * gm.z + be.z;
    o.w = (v3 - mu) * rstd * gm.w + be.w;
    *(float4*)&Y[(size_t)n * DD + c0] = o;
  }
}

// ---------------------------------------------------------------------------
__global__ void k_kt(const float* __restrict__ qkv, float* __restrict__ Kt) {
  const int st = blockIdx.x * 64;
  const int bh = blockIdx.y;
  const int b = bh >> 2, h = bh & 3;
  __shared__ float tile[64][33];
  const int tid = threadIdx.x;
  #pragma unroll
  for (int p = 0; p < 8; p++) {
    int sl = p * 8 + (tid >> 5);
    int d = tid & 31;
    tile[sl][d] = qkv[(size_t)(b * SS + st + sl) * 384 + 128 + h * 32 + d];
  }
  __syncthreads();
  int d = tid >> 3, s0 = (tid & 7) * 8;
  float* kt = Kt + ((size_t)bh * 32 + d) * 512 + st + s0;
  float4 v0, v1;
  v0.x = tile[s0 + 0][d]; v0.y = tile[s0 + 1][d]; v0.z = tile[s0 + 2][d]; v0.w = tile[s0 + 3][d];
  v1.x = tile[s0 + 4][d]; v1.y = tile[s0 + 5][d]; v1.z = tile[s0 + 6][d]; v1.w = tile[s0 + 7][d];
  *(float4*)kt = v0;
  *(float4*)(kt + 4) = v1;
}

// ---------------------------------------------------------------------------
// Fused attention. 1-D grid of 2048 with XCD-aware swizzle: all 8 q-tiles of a
// given bh get block ids congruent mod 8 -> same XCD -> K/V (128 KB) stays in
// that XCD's L2 (16 live bh x 128 KB = 2 MB < 4 MB).
__global__ __launch_bounds__(256, 4) void k_attn(const float* __restrict__ qkv,
                                                 const float* __restrict__ Kt,
                                                 const int* __restrict__ sent,
                                                 float* __restrict__ ctx) {
  const int id = blockIdx.x;
  const int xcd = id & 7;
  const int rem = id >> 3;
  const int qt = rem & 7;            // 0..7
  const int bh = xcd + 8 * (rem >> 3); // 0..255
  const int b = bh >> 2, h = bh & 3;
  const int tid = threadIdx.x;
  const int w = tid >> 6;
  const int lane = tid & 63;
  __shared__ float Ps[4][4][512];  // 32 KB

  int4 t0 = *(const int4*)&sent[b * SS + 4 * lane];
  int4 t1 = *(const int4*)&sent[b * SS + 256 + 4 * lane];
  float4 kb0, kb1;
  kb0.x = t0.x ? 0.f : -1e9f; kb0.y = t0.y ? 0.f : -1e9f;
  kb0.z = t0.z ? 0.f : -1e9f; kb0.w = t0.w ? 0.f : -1e9f;
  kb1.x = t1.x ? 0.f : -1e9f; kb1.y = t1.y ? 0.f : -1e9f;
  kb1.z = t1.z ? 0.f : -1e9f; kb1.w = t1.w ? 0.f : -1e9f;

  const int qbase = qt * 64 + w * 16;
  const float scale = 0.17677669529663687f; // 1/sqrt(32)
  const float* ktbase = Kt + (size_t)bh * 32 * 512 + 4 * lane;

  for (int g = 0; g < 4; g++) {
    const int row0 = qbase + g * 4;
    float4 s0[4], s1[4];
    #pragma unroll
    for (int r = 0; r < 4; r++) {
      s0[r].x = s0[r].y = s0[r].z = s0[r].w = 0.f;
      s1[r].x = s1[r].y = s1[r].z = s1[r].w = 0.f;
    }
    const float* qrow = qkv + (size_t)(b * SS + row0) * 384 + h * 32;
    #pragma unroll
    for (int dc = 0; dc < 8; dc++) {
      float4 q4[4];
      #pragma unroll
      for (int r = 0; r < 4; r++)
        q4[r] = *(const float4*)(qrow + (size_t)r * 384 + dc * 4);
      #pragma unroll
      for (int dd = 0; dd < 4; dd++) {
        const float* kp = ktbase + (size_t)(dc * 4 + dd) * 512;
        float4 k0 = *(const float4*)kp;
        float4 k1 = *(const float4*)(kp + 256);
        #pragma unroll
        for (int r = 0; r < 4; r++) {
          float qv = (dd == 0) ? q4[r].x : (dd == 1) ? q4[r].y : (dd == 2) ? q4[r].z : q4[r].w;
          s0[r].x = fmaf(qv, k0.x, s0[r].x); s0[r].y = fmaf(qv, k0.y, s0[r].y);
          s0[r].z = fmaf(qv, k0.z, s0[r].z); s0[r].w = fmaf(qv, k0.w, s0[r].w);
          s1[r].x = fmaf(qv, k1.x, s1[r].x); s1[r].y = fmaf(qv, k1.y, s1[r].y);
          s1[r].z = fmaf(qv, k1.z, s1[r].z); s1[r].w = fmaf(qv, k1.w, s1[r].w);
        }
      }
    }
    #pragma unroll
    for (int r = 0; r < 4; r++) {
      float4 a = s0[r], c = s1[r];
      a.x = fmaf(a.x, scale, kb0.x); a.y = fmaf(a.y, scale, kb0.y);
      a.z = fmaf(a.z, scale, kb0.z); a.w = fmaf(a.w, scale, kb0.w);
      c.x = fmaf(c.x, scale, kb1.x); c.y = fmaf(c.y, scale, kb1.y);
      c.z = fmaf(c.z, scale, kb1.z); c.w = fmaf(c.w, scale, kb1.w);
      float m = fmaxf(fmaxf(fmaxf(a.x, a.y), fmaxf(a.z, a.w)),
                      fmaxf(fmaxf(c.x, c.y), fmaxf(c.z, c.w)));
      #pragma unroll
      for (int off = 32; off >= 1; off >>= 1) m = fmaxf(m, __shfl_xor(m, off));
      a.x = expf(a.x - m); a.y = expf(a.y - m); a.z = expf(a.z - m); a.w = expf(a.w - m);
      c.x = expf(c.x - m); c.y = expf(c.y - m); c.z = expf(c.z - m); c.w = expf(c.w - m);
      float sum = a.x + a.y + a.z + a.w + c.x + c.y + c.z + c.w;
      #pragma unroll
      for (int off = 32; off >= 1; off >>= 1) sum += __shfl_xor(sum, off);
      float inv = 1.f / sum;
      a.x *= inv; a.y *= inv; a.z *= inv; a.w *= inv;
      c.x *= inv; c.y *= inv; c.z *= inv; c.w *= inv;
      *(float4*)&Ps[w][r][4 * lane] = a;
      *(float4*)&Ps[w][r][256 + 4 * lane] = c;
    }
    const int dl = lane & 7, rh = lane >> 3;
    const float* vbase = qkv + (size_t)(b * SS) * 384 + 256 + h * 32 + 4 * dl;
    float4 acc[4];
    #pragma unroll
    for (int r = 0; r < 4; r++) acc[r].x = acc[r].y = acc[r].z = acc[r].w = 0.f;
    #pragma unroll 4
    for (int t = 0; t < 16; t++) {
      int ks = 4 * rh + 32 * t;
      float4 p[4];
      #pragma unroll
      for (int r = 0; r < 4; r++) p[r] = *(const float4*)&Ps[w][r][ks];
      float4 v[4];
      #pragma unroll
      for (int kk = 0; kk < 4; kk++) v[kk] = *(const float4*)(vbase + (size_t)(ks + kk) * 384);
      #pragma unroll
      for (int r = 0; r < 4; r++) {
        acc[r].x = fmaf(p[r].x, v[0].x, acc[r].x);
        acc[r].y = fmaf(p[r].x, v[0].y, acc[r].y);
        acc[r].z = fmaf(p[r].x, v[0].z, acc[r].z);
        acc[r].w = fmaf(p[r].x, v[0].w, acc[r].w);
        acc[r].x = fmaf(p[r].y, v[1].x, acc[r].x);
        acc[r].y = fmaf(p[r].y, v[1].y, acc[r].y);
        acc[r].z = fmaf(p[r].y, v[1].z, acc[r].z);
        acc[r].w = fmaf(p[r].y, v[1].w, acc[r].w);
        acc[r].x = fmaf(p[r].z, v[2].x, acc[r].x);
        acc[r].y = fmaf(p[r].z, v[2].y, acc[r].y);
        acc[r].z = fmaf(p[r].z, v[2].z, acc[r].z);
        acc[r].w = fmaf(p[r].z, v[2].w, acc[r].w);
        acc[r].x = fmaf(p[r].w, v[3].x, acc[r].x);
        acc[r].y = fmaf(p[r].w, v[3].y, acc[r].y);
        acc[r].z = fmaf(p[r].w, v[3].z, acc[r].z);
        acc[r].w = fmaf(p[r].w, v[3].w, acc[r].w);
      }
    }
    #pragma unroll
    for (int off = 8; off <= 32; off <<= 1) {
      #pragma unroll
      for (int r = 0; r < 4; r++) {
        acc[r].x += __shfl_xor(acc[r].x, off);
        acc[r].y += __shfl_xor(acc[r].y, off);
        acc[r].z += __shfl_xor(acc[r].z, off);
        acc[r].w += __shfl_xor(acc[r].w, off);
      }
    }
    if (lane < 32) {
      int r = lane >> 3, d2 = lane & 7;
      float4 o;
      o.x = (r == 0) ? acc[0].x : (r == 1) ? acc[1].x : (r == 2) ? acc[2].x : acc[3].x;
      o.y = (r == 0) ? acc[0].y : (r == 1) ? acc[1].y : (r == 2) ? acc[2].y : acc[3].y;
      o.z = (r == 0) ? acc[0].z : (r == 1) ? acc[1].z : (r == 2) ? acc[2].z : acc[3].z;
      o.w = (r == 0) ? acc[0].w : (r == 1) ? acc[1].w : (r == 2) ? acc[2].w : acc[3].w;
      *(float4*)&ctx[(size_t)(b * SS + row0 + r) * DD + h * 32 + 4 * d2] = o;
    }
  }
}

// ---------------------------------------------------------------------------
__global__ void k_emis(const float* __restrict__ X, const float* __restrict__ Wtag,
                       const float* __restrict__ btag, float* __restrict__ em) {
  int idx = blockIdx.x * 256 + threadIdx.x;
  if (idx >= NN * TT) return;
  int n = idx / TT, t = idx - n * TT;
  const float* xr = X + (size_t)n * DD;
  const float* wr = Wtag + (size_t)t * DD;
  float acc = 0.f;
  #pragma unroll
  for (int k = 0; k < DD / 4; k++) {
    float4 x4 = *(const float4*)(xr + 4 * k);
    float4 w4 = *(const float4*)(wr + 4 * k);
    acc += x4.x * w4.x + x4.y * w4.y + x4.z * w4.z + x4.w * w4.w;
  }
  em[idx] = acc + btag[t];
}

// ---------------------------------------------------------------------------
__global__ void k_crf(const float* __restrict__ em, const int* __restrict__ sent,
                      const int* __restrict__ tags, const float* __restrict__ trans,
                      const float* __restrict__ start_t, const float* __restrict__ end_t,
                      float* __restrict__ part) {
  const int b = blockIdx.x;
  const int lane = threadIdx.x;
  const int j = (lane < TT) ? lane : 0;
  float tr[TT];
  #pragma unroll
  for (int i = 0; i < TT; i++) tr[i] = trans[i * TT + j];
  const float* emb_ = em + (size_t)b * SS * TT;
  float fv = start_t[j] + emb_[j];
  for (int s = 1; s < SS; s++) {
    int tok = sent[b * SS + s];
    if (tok != 0) {
      float a[TT];
      #pragma unroll
      for (int i = 0; i < TT; i++) a[i] = __shfl(fv, i) + tr[i];
      float m = a[0];
      #pragma unroll
      for (int i = 1; i < TT; i++) m = fmaxf(m, a[i]);
      float sum = 0.f;
      #pragma unroll
      for (int i = 0; i < TT; i++) sum += expf(a[i] - m);
      fv = emb_[s * TT + j] + m + logf(sum);
    }
  }
  float aa[TT];
  #pragma unroll
  for (int i = 0; i < TT; i++) aa[i] = __shfl(fv, i) + end_t[i];
  float m2 = aa[0];
  #pragma unroll
  for (int i = 1; i < TT; i++) m2 = fmaxf(m2, aa[i]);
  float sum2 = 0.f;
  #pragma unroll
  for (int i = 0; i < TT; i++) sum2 += expf(aa[i] - m2);
  float fwd = m2 + logf(sum2);
  float p = 0.f;
  int cnt = 0;
  #pragma unroll
  for (int ii = 0; ii < 8; ii++) {
    int s = lane + 64 * ii;
    cnt += (sent[b * SS + s] != 0) ? 1 : 0;
    int s2 = s + 1;
    if (s2 < SS && sent[b * SS + s2] != 0) {
      int tp = tags[b * SS + s2 - 1];
      int tc = tags[b * SS + s2];
      p += trans[tp * TT + tc] + emb_[(size_t)s2 * TT + tc];
    }
  }
  #pragma unroll
  for (int off = 32; off >= 1; off >>= 1) {
    p += __shfl_xor(p, off);
    cnt += __shfl_xor(cnt, off);
  }
  if (lane == 0) {
    int t0 = tags[b * SS];
    float score = start_t[t0] + emb_[t0] + p;
    int lastt = tags[b * SS + cnt - 1];
    score += end_t[lastt];
    part[b] = fwd - score;
  }
}

__global__ void k_final(const float* __restrict__ part, float* __restrict__ out) {
  float v = part[threadIdx.x];
  #pragma unroll
  for (int off = 32; off >= 1; off >>= 1) v += __shfl_xor(v, off);
  if (threadIdx.x == 0) out[0] = v * (1.f / 64.f);
}

// ---------------------------------------------------------------------------
extern "C" void kernel_launch(void* const* d_in, const int* in_sizes, int n_in,
                              void* d_out, int out_size, void* d_ws, size_t ws_size,
                              hipStream_t stream) {
  const int*   sent  = (const int*)d_in[0];
  const int*   tags  = (const int*)d_in[1];
  const float* emb   = (const float*)d_in[2];
  const float* Wqkv  = (const float*)d_in[3];
  const float* bqkv  = (const float*)d_in[4];
  const float* Wo    = (const float*)d_in[5];
  const float* bo    = (const float*)d_in[6];
  const float* W1    = (const float*)d_in[7];
  const float* b1f   = (const float*)d_in[8];
  const float* W2    = (const float*)d_in[9];
  const float* b2f   = (const float*)d_in[10];
  const float* ln1g  = (const float*)d_in[11];
  const float* ln1b  = (const float*)d_in[12];
  const float* ln2g  = (const float*)d_in[13];
  const float* ln2b  = (const float*)d_in[14];
  const float* Wtag  = (const float*)d_in[15];
  const float* btag  = (const float*)d_in[16];
  const float* trans = (const float*)d_in[17];
  const float* st    = (const float*)d_in[18];
  const float* et    = (const float*)d_in[19];

  float* ws   = (float*)d_ws;
  float* xA   = ws + OFF_X;
  float* xB   = ws + OFF_Y;
  float* qkv  = ws + OFF_QKV;
  float* ff   = ws + OFF_QKV;
  float* ctx  = ws + OFF_CTX;
  float* Kt   = ws + OFF_KT;
  float* em   = ws + OFF_EM;
  float* part = ws + OFF_PART;
  float* out  = (float*)d_out;

  k_embed<<<NN, DD, 0, stream>>>(sent, emb, xA);

  for (int l = 0; l < LL; l++) {
    k_gemm<128, false><<<dim3(NN / 64, 6), 256, 0, stream>>>(
        xA, Wqkv + (size_t)l * 3 * DD * DD, bqkv + l * 3 * DD, qkv, 3 * DD);
    k_kt<<<dim3(8, BB * HH), 256, 0, stream>>>(qkv, Kt);
    k_attn<<<dim3(2048), 256, 0, stream>>>(qkv, Kt, sent, ctx);
    k_gemm_ln<128><<<dim3(NN / 32), 256, 0, stream>>>(
        ctx, Wo + (size_t)l * DD * DD, bo + l * DD, xA, ln1g + l * DD, ln1b + l * DD, xB);
    k_gemm<128, true><<<dim3(NN / 64, 4), 256, 0, stream>>>(
        xB, W1 + (size_t)l * DFFc * DD, b1f + l * DFFc, ff, DFFc);
    k_gemm_ln<256><<<dim3(NN / 32), 256, 0, stream>>>(
        ff, W2 + (size_t)l * DD * DFFc, b2f + l * DD, xB, ln2g + l * DD, ln2b + l * DD, xA);
  }

  k_emis<<<(NN * TT + 255) / 256, 256, 0, stream>>>(xA, Wtag, btag, em);
  k_crf<<<BB, 64, 0, stream>>>(em, sent, tags, trans, st, et, part);
  k_final<<<1, 64, 0, stream>>>(part, out);
}

// Round 4
// 1511.472 us; speedup vs baseline: 1.7286x; 1.2590x over previous
//
#include <hip/hip_runtime.h>

// Problem constants
#define BB   64
#define SS   512
#define DD   128
#define DFFc 256
#define HH   4
#define TT   9
#define LL   2
#define HDc  32
#define NN   (BB*SS)   // 32768 tokens

// Workspace layout (float offsets)
#define OFF_X    0
#define OFF_Y    (NN*DD)
#define OFF_QKV  (2*NN*DD)          // 3*NN*DD floats; reused for FF hidden
#define OFF_CTX  (5*NN*DD)
#define OFF_KT   (6*NN*DD)
#define OFF_EM   (7*NN*DD)
#define OFF_PART (7*NN*DD + NN*TT)

// ---------------------------------------------------------------------------
__global__ void k_embed(const int* __restrict__ sent, const float* __restrict__ emb,
                        float* __restrict__ x) {
  int n = blockIdx.x;
  int d = threadIdx.x;
  int tok = sent[n];
  int s = n & (SS - 1);
  float e = (tok != 0) ? emb[(size_t)tok * DD + d] : 0.f;
  int i = d >> 1;
  float dv = expf((float)(2 * i) * (-9.210340371976184f / (float)DD));
  float ang = (float)s * dv;
  float pe = (d & 1) ? cosf(ang) : sinf(ang);
  x[(size_t)n * DD + d] = e + pe;
}

// ---------------------------------------------------------------------------
template <int KTOT, bool RELU>
__global__ __launch_bounds__(256) void k_gemm(const float* __restrict__ X,
                                              const float* __restrict__ W,
                                              const float* __restrict__ bias,
                                              float* __restrict__ Y, int ldY) {
  __shared__ float Xs[64][68];
  __shared__ float Wt[64][68];
  const int tid = threadIdx.x;
  const int tx = tid & 15, ty = tid >> 4;
  const int n0 = blockIdx.x * 64, c0g = blockIdx.y * 64;
  float acc[4][4] = {};
  for (int kb = 0; kb < KTOT; kb += 64) {
    #pragma unroll
    for (int p = 0; p < 4; p++) {
      int r = p * 16 + (tid >> 4);
      int c4 = (tid & 15) * 4;
      *(float4*)&Xs[r][c4] = *(const float4*)&X[(size_t)(n0 + r) * KTOT + kb + c4];
    }
    #pragma unroll
    for (int p = 0; p < 4; p++) {
      int c = (tid >> 4) + 16 * p;
      int kk0 = tid & 15;
      #pragma unroll
      for (int ii = 0; ii < 4; ii++)
        Wt[kk0 + 16 * ii][c] = W[(size_t)(c0g + c) * KTOT + kb + kk0 + 16 * ii];
    }
    __syncthreads();
    #pragma unroll
    for (int k4 = 0; k4 < 16; k4++) {
      float4 a4[4], b4[4];
      #pragma unroll
      for (int i = 0; i < 4; i++) a4[i] = *(const float4*)&Xs[4 * ty + i][4 * k4];
      #pragma unroll
      for (int k = 0; k < 4; k++) b4[k] = *(const float4*)&Wt[4 * k4 + k][4 * tx];
      #pragma unroll
      for (int k = 0; k < 4; k++) {
        #pragma unroll
        for (int i = 0; i < 4; i++) {
          float av = (k == 0) ? a4[i].x : (k == 1) ? a4[i].y : (k == 2) ? a4[i].z : a4[i].w;
          acc[i][0] = fmaf(av, b4[k].x, acc[i][0]);
          acc[i][1] = fmaf(av, b4[k].y, acc[i][1]);
          acc[i][2] = fmaf(av, b4[k].z, acc[i][2]);
          acc[i][3] = fmaf(av, b4[k].w, acc[i][3]);
        }
      }
    }
    __syncthreads();
  }
  float4 bi = *(const float4*)&bias[c0g + 4 * tx];
  #pragma unroll
  for (int i = 0; i < 4; i++) {
    float4 o;
    o.x = acc[i][0] + bi.x; o.y = acc[i][1] + bi.y;
    o.z = acc[i][2] + bi.z; o.w = acc[i][3] + bi.w;
    if (RELU) {
      o.x = fmaxf(o.x, 0.f); o.y = fmaxf(o.y, 0.f);
      o.z = fmaxf(o.z, 0.f); o.w = fmaxf(o.w, 0.f);
    }
    *(float4*)&Y[(size_t)(n0 + 4 * ty + i) * ldY + c0g + 4 * tx] = o;
  }
}

// ---------------------------------------------------------------------------
template <int KTOT>
__global__ __launch_bounds__(256) void k_gemm_ln(const float* __restrict__ X,
                                                 const float* __restrict__ W,
                                                 const float* __restrict__ bias,
                                                 const float* __restrict__ Res,
                                                 const float* __restrict__ gam,
                                                 const float* __restrict__ bet,
                                                 float* __restrict__ Y) {
  __shared__ float Xs[32][68];
  __shared__ float Wt[64][132];
  const int tid = threadIdx.x;
  const int tx = tid & 31, ty = tid >> 5;
  const int n0 = blockIdx.x * 32;
  float acc[4][4] = {};
  for (int kb = 0; kb < KTOT; kb += 64) {
    #pragma unroll
    for (int p = 0; p < 2; p++) {
      int r = p * 16 + (tid >> 4);
      int c4 = (tid & 15) * 4;
      *(float4*)&Xs[r][c4] = *(const float4*)&X[(size_t)(n0 + r) * KTOT + kb + c4];
    }
    #pragma unroll
    for (int p = 0; p < 8; p++) {
      int c = (tid >> 4) + 16 * p;
      int kk0 = tid & 15;
      #pragma unroll
      for (int ii = 0; ii < 4; ii++)
        Wt[kk0 + 16 * ii][c] = W[(size_t)c * KTOT + kb + kk0 + 16 * ii];
    }
    __syncthreads();
    #pragma unroll
    for (int k4 = 0; k4 < 16; k4++) {
      float4 a4[4], b4[4];
      #pragma unroll
      for (int i = 0; i < 4; i++) a4[i] = *(const float4*)&Xs[4 * ty + i][4 * k4];
      #pragma unroll
      for (int k = 0; k < 4; k++) b4[k] = *(const float4*)&Wt[4 * k4 + k][4 * tx];
      #pragma unroll
      for (int k = 0; k < 4; k++) {
        #pragma unroll
        for (int i = 0; i < 4; i++) {
          float av = (k == 0) ? a4[i].x : (k == 1) ? a4[i].y : (k == 2) ? a4[i].z : a4[i].w;
          acc[i][0] = fmaf(av, b4[k].x, acc[i][0]);
          acc[i][1] = fmaf(av, b4[k].y, acc[i][1]);
          acc[i][2] = fmaf(av, b4[k].z, acc[i][2]);
          acc[i][3] = fmaf(av, b4[k].w, acc[i][3]);
        }
      }
    }
    __syncthreads();
  }
  const int c0 = 4 * tx;
  float4 bi = *(const float4*)&bias[c0];
  float4 gm = *(const float4*)&gam[c0];
  float4 be = *(const float4*)&bet[c0];
  #pragma unroll
  for (int i = 0; i < 4; i++) {
    int n = n0 + 4 * ty + i;
    float4 rs = *(const float4*)&Res[(size_t)n * DD + c0];
    float v0 = acc[i][0] + bi.x + rs.x;
    float v1 = acc[i][1] + bi.y + rs.y;
    float v2 = acc[i][2] + bi.z + rs.z;
    float v3 = acc[i][3] + bi.w + rs.w;
    float s1 = v0 + v1 + v2 + v3;
    float s2 = v0 * v0 + v1 * v1 + v2 * v2 + v3 * v3;
    #pragma unroll
    for (int off = 16; off >= 1; off >>= 1) {
      s1 += __shfl_xor(s1, off);
      s2 += __shfl_xor(s2, off);
    }
    float mu = s1 * 0.0078125f;
    float var = s2 * 0.0078125f - mu * mu;
    float rstd = rsqrtf(var + 1e-5f);
    float4 o;
    o.x = (v0 - mu) * rstd * gm.x + be.x;
    o.y = (v1 - mu) * rstd * gm.y + be.y;
    o.z = (v2 - mu) * rstd * gm.z + be.z;
    o.w = (v3 - mu) * rstd * gm.w + be.w;
    *(float4*)&Y[(size_t)n * DD + c0] = o;
  }
}

// ---------------------------------------------------------------------------
__global__ void k_kt(const float* __restrict__ qkv, float* __restrict__ Kt) {
  const int st = blockIdx.x * 64;
  const int bh = blockIdx.y;
  const int b = bh >> 2, h = bh & 3;
  __shared__ float tile[64][33];
  const int tid = threadIdx.x;
  #pragma unroll
  for (int p = 0; p < 8; p++) {
    int sl = p * 8 + (tid >> 5);
    int d = tid & 31;
    tile[sl][d] = qkv[(size_t)(b * SS + st + sl) * 384 + 128 + h * 32 + d];
  }
  __syncthreads();
  int d = tid >> 3, s0 = (tid & 7) * 8;
  float* kt = Kt + ((size_t)bh * 32 + d) * 512 + st + s0;
  float4 v0, v1;
  v0.x = tile[s0 + 0][d]; v0.y = tile[s0 + 1][d]; v0.z = tile[s0 + 2][d]; v0.w = tile[s0 + 3][d];
  v1.x = tile[s0 + 4][d]; v1.y = tile[s0 + 5][d]; v1.z = tile[s0 + 6][d]; v1.w = tile[s0 + 7][d];
  *(float4*)kt = v0;
  *(float4*)(kt + 4) = v1;
}

// ---------------------------------------------------------------------------
// Fused attention. XCD-aware swizzle (proven by fetch delta r2->r3). NOTE:
// launch_bounds min-waves MUST stay at 2 — 4 forced a 64-VGPR cap and the
// kernel spilled ~1.5 GB/dispatch of scratch traffic (r2/r3 post-mortem).
__global__ __launch_bounds__(256, 2) void k_attn(const float* __restrict__ qkv,
                                                 const float* __restrict__ Kt,
                                                 const int* __restrict__ sent,
                                                 float* __restrict__ ctx) {
  const int id = blockIdx.x;
  const int xcd = id & 7;
  const int rem = id >> 3;
  const int qt = rem & 7;            // 0..7
  const int bh = xcd + 8 * (rem >> 3); // 0..255
  const int b = bh >> 2, h = bh & 3;
  const int tid = threadIdx.x;
  const int w = tid >> 6;
  const int lane = tid & 63;
  __shared__ float Ps[4][4][512];  // 32 KB

  int4 t0 = *(const int4*)&sent[b * SS + 4 * lane];
  int4 t1 = *(const int4*)&sent[b * SS + 256 + 4 * lane];
  float4 kb0, kb1;
  kb0.x = t0.x ? 0.f : -1e9f; kb0.y = t0.y ? 0.f : -1e9f;
  kb0.z = t0.z ? 0.f : -1e9f; kb0.w = t0.w ? 0.f : -1e9f;
  kb1.x = t1.x ? 0.f : -1e9f; kb1.y = t1.y ? 0.f : -1e9f;
  kb1.z = t1.z ? 0.f : -1e9f; kb1.w = t1.w ? 0.f : -1e9f;

  const int qbase = qt * 64 + w * 16;
  const float scale = 0.17677669529663687f; // 1/sqrt(32)
  const float* ktbase = Kt + (size_t)bh * 32 * 512 + 4 * lane;

  for (int g = 0; g < 4; g++) {
    const int row0 = qbase + g * 4;
    float4 s0[4], s1[4];
    #pragma unroll
    for (int r = 0; r < 4; r++) {
      s0[r].x = s0[r].y = s0[r].z = s0[r].w = 0.f;
      s1[r].x = s1[r].y = s1[r].z = s1[r].w = 0.f;
    }
    const float* qrow = qkv + (size_t)(b * SS + row0) * 384 + h * 32;
    #pragma unroll
    for (int dc = 0; dc < 8; dc++) {
      float4 q4[4];
      #pragma unroll
      for (int r = 0; r < 4; r++)
        q4[r] = *(const float4*)(qrow + (size_t)r * 384 + dc * 4);
      #pragma unroll
      for (int dd = 0; dd < 4; dd++) {
        const float* kp = ktbase + (size_t)(dc * 4 + dd) * 512;
        float4 k0 = *(const float4*)kp;
        float4 k1 = *(const float4*)(kp + 256);
        #pragma unroll
        for (int r = 0; r < 4; r++) {
          float qv = (dd == 0) ? q4[r].x : (dd == 1) ? q4[r].y : (dd == 2) ? q4[r].z : q4[r].w;
          s0[r].x = fmaf(qv, k0.x, s0[r].x); s0[r].y = fmaf(qv, k0.y, s0[r].y);
          s0[r].z = fmaf(qv, k0.z, s0[r].z); s0[r].w = fmaf(qv, k0.w, s0[r].w);
          s1[r].x = fmaf(qv, k1.x, s1[r].x); s1[r].y = fmaf(qv, k1.y, s1[r].y);
          s1[r].z = fmaf(qv, k1.z, s1[r].z); s1[r].w = fmaf(qv, k1.w, s1[r].w);
        }
      }
    }
    #pragma unroll
    for (int r = 0; r < 4; r++) {
      float4 a = s0[r], c = s1[r];
      a.x = fmaf(a.x, scale, kb0.x); a.y = fmaf(a.y, scale, kb0.y);
      a.z = fmaf(a.z, scale, kb0.z); a.w = fmaf(a.w, scale, kb0.w);
      c.x = fmaf(c.x, scale, kb1.x); c.y = fmaf(c.y, scale, kb1.y);
      c.z = fmaf(c.z, scale, kb1.z); c.w = fmaf(c.w, scale, kb1.w);
      float m = fmaxf(fmaxf(fmaxf(a.x, a.y), fmaxf(a.z, a.w)),
                      fmaxf(fmaxf(c.x, c.y), fmaxf(c.z, c.w)));
      #pragma unroll
      for (int off = 32; off >= 1; off >>= 1) m = fmaxf(m, __shfl_xor(m, off));
      a.x = expf(a.x - m); a.y = expf(a.y - m); a.z = expf(a.z - m); a.w = expf(a.w - m);
      c.x = expf(c.x - m); c.y = expf(c.y - m); c.z = expf(c.z - m); c.w = expf(c.w - m);
      float sum = a.x + a.y + a.z + a.w + c.x + c.y + c.z + c.w;
      #pragma unroll
      for (int off = 32; off >= 1; off >>= 1) sum += __shfl_xor(sum, off);
      float inv = 1.f / sum;
      a.x *= inv; a.y *= inv; a.z *= inv; a.w *= inv;
      c.x *= inv; c.y *= inv; c.z *= inv; c.w *= inv;
      *(float4*)&Ps[w][r][4 * lane] = a;
      *(float4*)&Ps[w][r][256 + 4 * lane] = c;
    }
    const int dl = lane & 7, rh = lane >> 3;
    const float* vbase = qkv + (size_t)(b * SS) * 384 + 256 + h * 32 + 4 * dl;
    float4 acc[4];
    #pragma unroll
    for (int r = 0; r < 4; r++) acc[r].x = acc[r].y = acc[r].z = acc[r].w = 0.f;
    #pragma unroll 4
    for (int t = 0; t < 16; t++) {
      int ks = 4 * rh + 32 * t;
      float4 p[4];
      #pragma unroll
      for (int r = 0; r < 4; r++) p[r] = *(const float4*)&Ps[w][r][ks];
      float4 v[4];
      #pragma unroll
      for (int kk = 0; kk < 4; kk++) v[kk] = *(const float4*)(vbase + (size_t)(ks + kk) * 384);
      #pragma unroll
      for (int r = 0; r < 4; r++) {
        acc[r].x = fmaf(p[r].x, v[0].x, acc[r].x);
        acc[r].y = fmaf(p[r].x, v[0].y, acc[r].y);
        acc[r].z = fmaf(p[r].x, v[0].z, acc[r].z);
        acc[r].w = fmaf(p[r].x, v[0].w, acc[r].w);
        acc[r].x = fmaf(p[r].y, v[1].x, acc[r].x);
        acc[r].y = fmaf(p[r].y, v[1].y, acc[r].y);
        acc[r].z = fmaf(p[r].y, v[1].z, acc[r].z);
        acc[r].w = fmaf(p[r].y, v[1].w, acc[r].w);
        acc[r].x = fmaf(p[r].z, v[2].x, acc[r].x);
        acc[r].y = fmaf(p[r].z, v[2].y, acc[r].y);
        acc[r].z = fmaf(p[r].z, v[2].z, acc[r].z);
        acc[r].w = fmaf(p[r].z, v[2].w, acc[r].w);
        acc[r].x = fmaf(p[r].w, v[3].x, acc[r].x);
        acc[r].y = fmaf(p[r].w, v[3].y, acc[r].y);
        acc[r].z = fmaf(p[r].w, v[3].z, acc[r].z);
        acc[r].w = fmaf(p[r].w, v[3].w, acc[r].w);
      }
    }
    #pragma unroll
    for (int off = 8; off <= 32; off <<= 1) {
      #pragma unroll
      for (int r = 0; r < 4; r++) {
        acc[r].x += __shfl_xor(acc[r].x, off);
        acc[r].y += __shfl_xor(acc[r].y, off);
        acc[r].z += __shfl_xor(acc[r].z, off);
        acc[r].w += __shfl_xor(acc[r].w, off);
      }
    }
    if (lane < 32) {
      int r = lane >> 3, d2 = lane & 7;
      float4 o;
      o.x = (r == 0) ? acc[0].x : (r == 1) ? acc[1].x : (r == 2) ? acc[2].x : acc[3].x;
      o.y = (r == 0) ? acc[0].y : (r == 1) ? acc[1].y : (r == 2) ? acc[2].y : acc[3].y;
      o.z = (r == 0) ? acc[0].z : (r == 1) ? acc[1].z : (r == 2) ? acc[2].z : acc[3].z;
      o.w = (r == 0) ? acc[0].w : (r == 1) ? acc[1].w : (r == 2) ? acc[2].w : acc[3].w;
      *(float4*)&ctx[(size_t)(b * SS + row0 + r) * DD + h * 32 + 4 * d2] = o;
    }
  }
}

// ---------------------------------------------------------------------------
__global__ void k_emis(const float* __restrict__ X, const float* __restrict__ Wtag,
                       const float* __restrict__ btag, float* __restrict__ em) {
  int idx = blockIdx.x * 256 + threadIdx.x;
  if (idx >= NN * TT) return;
  int n = idx / TT, t = idx - n * TT;
  const float* xr = X + (size_t)n * DD;
  const float* wr = Wtag + (size_t)t * DD;
  float acc = 0.f;
  #pragma unroll
  for (int k = 0; k < DD / 4; k++) {
    float4 x4 = *(const float4*)(xr + 4 * k);
    float4 w4 = *(const float4*)(wr + 4 * k);
    acc += x4.x * w4.x + x4.y * w4.y + x4.z * w4.z + x4.w * w4.w;
  }
  em[idx] = acc + btag[t];
}

// ---------------------------------------------------------------------------
__global__ void k_crf(const float* __restrict__ em, const int* __restrict__ sent,
                      const int* __restrict__ tags, const float* __restrict__ trans,
                      const float* __restrict__ start_t, const float* __restrict__ end_t,
                      float* __restrict__ part) {
  const int b = blockIdx.x;
  const int lane = threadIdx.x;
  const int j = (lane < TT) ? lane : 0;
  float tr[TT];
  #pragma unroll
  for (int i = 0; i < TT; i++) tr[i] = trans[i * TT + j];
  const float* emb_ = em + (size_t)b * SS * TT;
  float fv = start_t[j] + emb_[j];
  for (int s = 1; s < SS; s++) {
    int tok = sent[b * SS + s];
    if (tok != 0) {
      float a[TT];
      #pragma unroll
      for (int i = 0; i < TT; i++) a[i] = __shfl(fv, i) + tr[i];
      float m = a[0];
      #pragma unroll
      for (int i = 1; i < TT; i++) m = fmaxf(m, a[i]);
      float sum = 0.f;
      #pragma unroll
      for (int i = 0; i < TT; i++) sum += expf(a[i] - m);
      fv = emb_[s * TT + j] + m + logf(sum);
    }
  }
  float aa[TT];
  #pragma unroll
  for (int i = 0; i < TT; i++) aa[i] = __shfl(fv, i) + end_t[i];
  float m2 = aa[0];
  #pragma unroll
  for (int i = 1; i < TT; i++) m2 = fmaxf(m2, aa[i]);
  float sum2 = 0.f;
  #pragma unroll
  for (int i = 0; i < TT; i++) sum2 += expf(aa[i] - m2);
  float fwd = m2 + logf(sum2);
  float p = 0.f;
  int cnt = 0;
  #pragma unroll
  for (int ii = 0; ii < 8; ii++) {
    int s = lane + 64 * ii;
    cnt += (sent[b * SS + s] != 0) ? 1 : 0;
    int s2 = s + 1;
    if (s2 < SS && sent[b * SS + s2] != 0) {
      int tp = tags[b * SS + s2 - 1];
      int tc = tags[b * SS + s2];
      p += trans[tp * TT + tc] + emb_[(size_t)s2 * TT + tc];
    }
  }
  #pragma unroll
  for (int off = 32; off >= 1; off >>= 1) {
    p += __shfl_xor(p, off);
    cnt += __shfl_xor(cnt, off);
  }
  if (lane == 0) {
    int t0 = tags[b * SS];
    float score = start_t[t0] + emb_[t0] + p;
    int lastt = tags[b * SS + cnt - 1];
    score += end_t[lastt];
    part[b] = fwd - score;
  }
}

__global__ void k_final(const float* __restrict__ part, float* __restrict__ out) {
  float v = part[threadIdx.x];
  #pragma unroll
  for (int off = 32; off >= 1; off >>= 1) v += __shfl_xor(v, off);
  if (threadIdx.x == 0) out[0] = v * (1.f / 64.f);
}

// ---------------------------------------------------------------------------
extern "C" void kernel_launch(void* const* d_in, const int* in_sizes, int n_in,
                              void* d_out, int out_size, void* d_ws, size_t ws_size,
                              hipStream_t stream) {
  const int*   sent  = (const int*)d_in[0];
  const int*   tags  = (const int*)d_in[1];
  const float* emb   = (const float*)d_in[2];
  const float* Wqkv  = (const float*)d_in[3];
  const float* bqkv  = (const float*)d_in[4];
  const float* Wo    = (const float*)d_in[5];
  const float* bo    = (const float*)d_in[6];
  const float* W1    = (const float*)d_in[7];
  const float* b1f   = (const float*)d_in[8];
  const float* W2    = (const float*)d_in[9];
  const float* b2f   = (const float*)d_in[10];
  const float* ln1g  = (const float*)d_in[11];
  const float* ln1b  = (const float*)d_in[12];
  const float* ln2g  = (const float*)d_in[13];
  const float* ln2b  = (const float*)d_in[14];
  const float* Wtag  = (const float*)d_in[15];
  const float* btag  = (const float*)d_in[16];
  const float* trans = (const float*)d_in[17];
  const float* st    = (const float*)d_in[18];
  const float* et    = (const float*)d_in[19];

  float* ws   = (float*)d_ws;
  float* xA   = ws + OFF_X;
  float* xB   = ws + OFF_Y;
  float* qkv  = ws + OFF_QKV;
  float* ff   = ws + OFF_QKV;
  float* ctx  = ws + OFF_CTX;
  float* Kt   = ws + OFF_KT;
  float* em   = ws + OFF_EM;
  float* part = ws + OFF_PART;
  float* out  = (float*)d_out;

  k_embed<<<NN, DD, 0, stream>>>(sent, emb, xA);

  for (int l = 0; l < LL; l++) {
    k_gemm<128, false><<<dim3(NN / 64, 6), 256, 0, stream>>>(
        xA, Wqkv + (size_t)l * 3 * DD * DD, bqkv + l * 3 * DD, qkv, 3 * DD);
    k_kt<<<dim3(8, BB * HH), 256, 0, stream>>>(qkv, Kt);
    k_attn<<<dim3(2048), 256, 0, stream>>>(qkv, Kt, sent, ctx);
    k_gemm_ln<128><<<dim3(NN / 32), 256, 0, stream>>>(
        ctx, Wo + (size_t)l * DD * DD, bo + l * DD, xA, ln1g + l * DD, ln1b + l * DD, xB);
    k_gemm<128, true><<<dim3(NN / 64, 4), 256, 0, stream>>>(
        xB, W1 + (size_t)l * DFFc * DD, b1f + l * DFFc, ff, DFFc);
    k_gemm_ln<256><<<dim3(NN / 32), 256, 0, stream>>>(
        ff, W2 + (size_t)l * DD * DFFc, b2f + l * DD, xB, ln2g + l * DD, ln2b + l * DD, xA);
  }

  k_emis<<<(NN * TT + 255) / 256, 256, 0, stream>>>(xA, Wtag, btag, em);
  k_crf<<<BB, 64, 0, stream>>>(em, sent, tags, trans, st, et, part);
  k_final<<<1, 64, 0, stream>>>(part, out);
}

// Round 5
// 1481.434 us; speedup vs baseline: 1.7636x; 1.0203x over previous
//
#include <hip/hip_runtime.h>

// Problem constants
#define BB   64
#define SS   512
#define DD   128
#define DFFc 256
#define HH   4
#define TT   9
#define LL   2
#define HDc  32
#define NN   (BB*SS)   // 32768 tokens

// Workspace layout (float offsets)
#define OFF_X    0
#define OFF_Y    (NN*DD)
#define OFF_QKV  (2*NN*DD)          // 3*NN*DD floats; reused for FF hidden
#define OFF_CTX  (5*NN*DD)
#define OFF_KT   (6*NN*DD)
#define OFF_EM   (7*NN*DD)
#define OFF_PART (7*NN*DD + NN*TT)

// ---------------------------------------------------------------------------
__global__ void k_embed(const int* __restrict__ sent, const float* __restrict__ emb,
                        float* __restrict__ x) {
  int n = blockIdx.x;
  int d = threadIdx.x;
  int tok = sent[n];
  int s = n & (SS - 1);
  float e = (tok != 0) ? emb[(size_t)tok * DD + d] : 0.f;
  int i = d >> 1;
  float dv = expf((float)(2 * i) * (-9.210340371976184f / (float)DD));
  float ang = (float)s * dv;
  float pe = (d & 1) ? cosf(ang) : sinf(ang);
  x[(size_t)n * DD + d] = e + pe;
}

// ---------------------------------------------------------------------------
template <int KTOT, bool RELU>
__global__ __launch_bounds__(256) void k_gemm(const float* __restrict__ X,
                                              const float* __restrict__ W,
                                              const float* __restrict__ bias,
                                              float* __restrict__ Y, int ldY) {
  __shared__ float Xs[64][68];
  __shared__ float Wt[64][68];
  const int tid = threadIdx.x;
  const int tx = tid & 15, ty = tid >> 4;
  const int n0 = blockIdx.x * 64, c0g = blockIdx.y * 64;
  float acc[4][4] = {};
  for (int kb = 0; kb < KTOT; kb += 64) {
    #pragma unroll
    for (int p = 0; p < 4; p++) {
      int r = p * 16 + (tid >> 4);
      int c4 = (tid & 15) * 4;
      *(float4*)&Xs[r][c4] = *(const float4*)&X[(size_t)(n0 + r) * KTOT + kb + c4];
    }
    #pragma unroll
    for (int p = 0; p < 4; p++) {
      int c = (tid >> 4) + 16 * p;
      int kk0 = tid & 15;
      #pragma unroll
      for (int ii = 0; ii < 4; ii++)
        Wt[kk0 + 16 * ii][c] = W[(size_t)(c0g + c) * KTOT + kb + kk0 + 16 * ii];
    }
    __syncthreads();
    #pragma unroll
    for (int k4 = 0; k4 < 16; k4++) {
      float4 a4[4], b4[4];
      #pragma unroll
      for (int i = 0; i < 4; i++) a4[i] = *(const float4*)&Xs[4 * ty + i][4 * k4];
      #pragma unroll
      for (int k = 0; k < 4; k++) b4[k] = *(const float4*)&Wt[4 * k4 + k][4 * tx];
      #pragma unroll
      for (int k = 0; k < 4; k++) {
        #pragma unroll
        for (int i = 0; i < 4; i++) {
          float av = (k == 0) ? a4[i].x : (k == 1) ? a4[i].y : (k == 2) ? a4[i].z : a4[i].w;
          acc[i][0] = fmaf(av, b4[k].x, acc[i][0]);
          acc[i][1] = fmaf(av, b4[k].y, acc[i][1]);
          acc[i][2] = fmaf(av, b4[k].z, acc[i][2]);
          acc[i][3] = fmaf(av, b4[k].w, acc[i][3]);
        }
      }
    }
    __syncthreads();
  }
  float4 bi = *(const float4*)&bias[c0g + 4 * tx];
  #pragma unroll
  for (int i = 0; i < 4; i++) {
    float4 o;
    o.x = acc[i][0] + bi.x; o.y = acc[i][1] + bi.y;
    o.z = acc[i][2] + bi.z; o.w = acc[i][3] + bi.w;
    if (RELU) {
      o.x = fmaxf(o.x, 0.f); o.y = fmaxf(o.y, 0.f);
      o.z = fmaxf(o.z, 0.f); o.w = fmaxf(o.w, 0.f);
    }
    *(float4*)&Y[(size_t)(n0 + 4 * ty + i) * ldY + c0g + 4 * tx] = o;
  }
}

// ---------------------------------------------------------------------------
template <int KTOT>
__global__ __launch_bounds__(256) void k_gemm_ln(const float* __restrict__ X,
                                                 const float* __restrict__ W,
                                                 const float* __restrict__ bias,
                                                 const float* __restrict__ Res,
                                                 const float* __restrict__ gam,
                                                 const float* __restrict__ bet,
                                                 float* __restrict__ Y) {
  __shared__ float Xs[32][68];
  __shared__ float Wt[64][132];
  const int tid = threadIdx.x;
  const int tx = tid & 31, ty = tid >> 5;
  const int n0 = blockIdx.x * 32;
  float acc[4][4] = {};
  for (int kb = 0; kb < KTOT; kb += 64) {
    #pragma unroll
    for (int p = 0; p < 2; p++) {
      int r = p * 16 + (tid >> 4);
      int c4 = (tid & 15) * 4;
      *(float4*)&Xs[r][c4] = *(const float4*)&X[(size_t)(n0 + r) * KTOT + kb + c4];
    }
    #pragma unroll
    for (int p = 0; p < 8; p++) {
      int c = (tid >> 4) + 16 * p;
      int kk0 = tid & 15;
      #pragma unroll
      for (int ii = 0; ii < 4; ii++)
        Wt[kk0 + 16 * ii][c] = W[(size_t)c * KTOT + kb + kk0 + 16 * ii];
    }
    __syncthreads();
    #pragma unroll
    for (int k4 = 0; k4 < 16; k4++) {
      float4 a4[4], b4[4];
      #pragma unroll
      for (int i = 0; i < 4; i++) a4[i] = *(const float4*)&Xs[4 * ty + i][4 * k4];
      #pragma unroll
      for (int k = 0; k < 4; k++) b4[k] = *(const float4*)&Wt[4 * k4 + k][4 * tx];
      #pragma unroll
      for (int k = 0; k < 4; k++) {
        #pragma unroll
        for (int i = 0; i < 4; i++) {
          float av = (k == 0) ? a4[i].x : (k == 1) ? a4[i].y : (k == 2) ? a4[i].z : a4[i].w;
          acc[i][0] = fmaf(av, b4[k].x, acc[i][0]);
          acc[i][1] = fmaf(av, b4[k].y, acc[i][1]);
          acc[i][2] = fmaf(av, b4[k].z, acc[i][2]);
          acc[i][3] = fmaf(av, b4[k].w, acc[i][3]);
        }
      }
    }
    __syncthreads();
  }
  const int c0 = 4 * tx;
  float4 bi = *(const float4*)&bias[c0];
  float4 gm = *(const float4*)&gam[c0];
  float4 be = *(const float4*)&bet[c0];
  #pragma unroll
  for (int i = 0; i < 4; i++) {
    int n = n0 + 4 * ty + i;
    float4 rs = *(const float4*)&Res[(size_t)n * DD + c0];
    float v0 = acc[i][0] + bi.x + rs.x;
    float v1 = acc[i][1] + bi.y + rs.y;
    float v2 = acc[i][2] + bi.z + rs.z;
    float v3 = acc[i][3] + bi.w + rs.w;
    float s1 = v0 + v1 + v2 + v3;
    float s2 = v0 * v0 + v1 * v1 + v2 * v2 + v3 * v3;
    #pragma unroll
    for (int off = 16; off >= 1; off >>= 1) {
      s1 += __shfl_xor(s1, off);
      s2 += __shfl_xor(s2, off);
    }
    float mu = s1 * 0.0078125f;
    float var = s2 * 0.0078125f - mu * mu;
    float rstd = rsqrtf(var + 1e-5f);
    float4 o;
    o.x = (v0 - mu) * rstd * gm.x + be.x;
    o.y = (v1 - mu) * rstd * gm.y + be.y;
    o.z = (v2 - mu) * rstd * gm.z + be.z;
    o.w = (v3 - mu) * rstd * gm.w + be.w;
    *(float4*)&Y[(size_t)n * DD + c0] = o;
  }
}

// ---------------------------------------------------------------------------
__global__ void k_kt(const float* __restrict__ qkv, float* __restrict__ Kt) {
  const int st = blockIdx.x * 64;
  const int bh = blockIdx.y;
  const int b = bh >> 2, h = bh & 3;
  __shared__ float tile[64][33];
  const int tid = threadIdx.x;
  #pragma unroll
  for (int p = 0; p < 8; p++) {
    int sl = p * 8 + (tid >> 5);
    int d = tid & 31;
    tile[sl][d] = qkv[(size_t)(b * SS + st + sl) * 384 + 128 + h * 32 + d];
  }
  __syncthreads();
  int d = tid >> 3, s0 = (tid & 7) * 8;
  float* kt = Kt + ((size_t)bh * 32 + d) * 512 + st + s0;
  float4 v0, v1;
  v0.x = tile[s0 + 0][d]; v0.y = tile[s0 + 1][d]; v0.z = tile[s0 + 2][d]; v0.w = tile[s0 + 3][d];
  v1.x = tile[s0 + 4][d]; v1.y = tile[s0 + 5][d]; v1.z = tile[s0 + 6][d]; v1.w = tile[s0 + 7][d];
  *(float4*)kt = v0;
  *(float4*)(kt + 4) = v1;
}

// ---------------------------------------------------------------------------
// Fused attention. XCD-aware swizzle (proven by fetch delta r2->r3).
// REGISTER-PRESSURE HISTORY: launch_bounds(256,4) => 64-VGPR cap, ~1.5 GB
// spill traffic (r2/r3). (256,2) => 128-VGPR cap, still ~420 MB spill (r4).
// Plain (256) lets the allocator pick ~180 VGPR with ZERO spill (r1 evidence:
// WRITE_SIZE was exactly the 16 MB ctx write). Occupancy stays 2 waves/SIMD;
// ILP (32 indep FMA per K-load pair) covers it.
__global__ __launch_bounds__(256) void k_attn(const float* __restrict__ qkv,
                                              const float* __restrict__ Kt,
                                              const int* __restrict__ sent,
                                              float* __restrict__ ctx) {
  const int id = blockIdx.x;
  const int xcd = id & 7;
  const int rem = id >> 3;
  const int qt = rem & 7;            // 0..7
  const int bh = xcd + 8 * (rem >> 3); // 0..255
  const int b = bh >> 2, h = bh & 3;
  const int tid = threadIdx.x;
  const int w = tid >> 6;
  const int lane = tid & 63;
  __shared__ float Ps[4][4][512];  // 32 KB

  int4 t0 = *(const int4*)&sent[b * SS + 4 * lane];
  int4 t1 = *(const int4*)&sent[b * SS + 256 + 4 * lane];
  float4 kb0, kb1;
  kb0.x = t0.x ? 0.f : -1e9f; kb0.y = t0.y ? 0.f : -1e9f;
  kb0.z = t0.z ? 0.f : -1e9f; kb0.w = t0.w ? 0.f : -1e9f;
  kb1.x = t1.x ? 0.f : -1e9f; kb1.y = t1.y ? 0.f : -1e9f;
  kb1.z = t1.z ? 0.f : -1e9f; kb1.w = t1.w ? 0.f : -1e9f;

  const int qbase = qt * 64 + w * 16;
  const float scale = 0.17677669529663687f; // 1/sqrt(32)
  const float* ktbase = Kt + (size_t)bh * 32 * 512 + 4 * lane;

  for (int g = 0; g < 4; g++) {
    const int row0 = qbase + g * 4;
    float4 s0[4], s1[4];
    #pragma unroll
    for (int r = 0; r < 4; r++) {
      s0[r].x = s0[r].y = s0[r].z = s0[r].w = 0.f;
      s1[r].x = s1[r].y = s1[r].z = s1[r].w = 0.f;
    }
    const float* qrow = qkv + (size_t)(b * SS + row0) * 384 + h * 32;
    #pragma unroll
    for (int dc = 0; dc < 8; dc++) {
      float4 q4[4];
      #pragma unroll
      for (int r = 0; r < 4; r++)
        q4[r] = *(const float4*)(qrow + (size_t)r * 384 + dc * 4);
      #pragma unroll
      for (int dd = 0; dd < 4; dd++) {
        const float* kp = ktbase + (size_t)(dc * 4 + dd) * 512;
        float4 k0 = *(const float4*)kp;
        float4 k1 = *(const float4*)(kp + 256);
        #pragma unroll
        for (int r = 0; r < 4; r++) {
          float qv = (dd == 0) ? q4[r].x : (dd == 1) ? q4[r].y : (dd == 2) ? q4[r].z : q4[r].w;
          s0[r].x = fmaf(qv, k0.x, s0[r].x); s0[r].y = fmaf(qv, k0.y, s0[r].y);
          s0[r].z = fmaf(qv, k0.z, s0[r].z); s0[r].w = fmaf(qv, k0.w, s0[r].w);
          s1[r].x = fmaf(qv, k1.x, s1[r].x); s1[r].y = fmaf(qv, k1.y, s1[r].y);
          s1[r].z = fmaf(qv, k1.z, s1[r].z); s1[r].w = fmaf(qv, k1.w, s1[r].w);
        }
      }
    }
    #pragma unroll
    for (int r = 0; r < 4; r++) {
      float4 a = s0[r], c = s1[r];
      a.x = fmaf(a.x, scale, kb0.x); a.y = fmaf(a.y, scale, kb0.y);
      a.z = fmaf(a.z, scale, kb0.z); a.w = fmaf(a.w, scale, kb0.w);
      c.x = fmaf(c.x, scale, kb1.x); c.y = fmaf(c.y, scale, kb1.y);
      c.z = fmaf(c.z, scale, kb1.z); c.w = fmaf(c.w, scale, kb1.w);
      float m = fmaxf(fmaxf(fmaxf(a.x, a.y), fmaxf(a.z, a.w)),
                      fmaxf(fmaxf(c.x, c.y), fmaxf(c.z, c.w)));
      #pragma unroll
      for (int off = 32; off >= 1; off >>= 1) m = fmaxf(m, __shfl_xor(m, off));
      a.x = expf(a.x - m); a.y = expf(a.y - m); a.z = expf(a.z - m); a.w = expf(a.w - m);
      c.x = expf(c.x - m); c.y = expf(c.y - m); c.z = expf(c.z - m); c.w = expf(c.w - m);
      float sum = a.x + a.y + a.z + a.w + c.x + c.y + c.z + c.w;
      #pragma unroll
      for (int off = 32; off >= 1; off >>= 1) sum += __shfl_xor(sum, off);
      float inv = 1.f / sum;
      a.x *= inv; a.y *= inv; a.z *= inv; a.w *= inv;
      c.x *= inv; c.y *= inv; c.z *= inv; c.w *= inv;
      *(float4*)&Ps[w][r][4 * lane] = a;
      *(float4*)&Ps[w][r][256 + 4 * lane] = c;
    }
    const int dl = lane & 7, rh = lane >> 3;
    const float* vbase = qkv + (size_t)(b * SS) * 384 + 256 + h * 32 + 4 * dl;
    float4 acc[4];
    #pragma unroll
    for (int r = 0; r < 4; r++) acc[r].x = acc[r].y = acc[r].z = acc[r].w = 0.f;
    #pragma unroll 4
    for (int t = 0; t < 16; t++) {
      int ks = 4 * rh + 32 * t;
      float4 p[4];
      #pragma unroll
      for (int r = 0; r < 4; r++) p[r] = *(const float4*)&Ps[w][r][ks];
      float4 v[4];
      #pragma unroll
      for (int kk = 0; kk < 4; kk++) v[kk] = *(const float4*)(vbase + (size_t)(ks + kk) * 384);
      #pragma unroll
      for (int r = 0; r < 4; r++) {
        acc[r].x = fmaf(p[r].x, v[0].x, acc[r].x);
        acc[r].y = fmaf(p[r].x, v[0].y, acc[r].y);
        acc[r].z = fmaf(p[r].x, v[0].z, acc[r].z);
        acc[r].w = fmaf(p[r].x, v[0].w, acc[r].w);
        acc[r].x = fmaf(p[r].y, v[1].x, acc[r].x);
        acc[r].y = fmaf(p[r].y, v[1].y, acc[r].y);
        acc[r].z = fmaf(p[r].y, v[1].z, acc[r].z);
        acc[r].w = fmaf(p[r].y, v[1].w, acc[r].w);
        acc[r].x = fmaf(p[r].z, v[2].x, acc[r].x);
        acc[r].y = fmaf(p[r].z, v[2].y, acc[r].y);
        acc[r].z = fmaf(p[r].z, v[2].z, acc[r].z);
        acc[r].w = fmaf(p[r].z, v[2].w, acc[r].w);
        acc[r].x = fmaf(p[r].w, v[3].x, acc[r].x);
        acc[r].y = fmaf(p[r].w, v[3].y, acc[r].y);
        acc[r].z = fmaf(p[r].w, v[3].z, acc[r].z);
        acc[r].w = fmaf(p[r].w, v[3].w, acc[r].w);
      }
    }
    #pragma unroll
    for (int off = 8; off <= 32; off <<= 1) {
      #pragma unroll
      for (int r = 0; r < 4; r++) {
        acc[r].x += __shfl_xor(acc[r].x, off);
        acc[r].y += __shfl_xor(acc[r].y, off);
        acc[r].z += __shfl_xor(acc[r].z, off);
        acc[r].w += __shfl_xor(acc[r].w, off);
      }
    }
    if (lane < 32) {
      int r = lane >> 3, d2 = lane & 7;
      float4 o;
      o.x = (r == 0) ? acc[0].x : (r == 1) ? acc[1].x : (r == 2) ? acc[2].x : acc[3].x;
      o.y = (r == 0) ? acc[0].y : (r == 1) ? acc[1].y : (r == 2) ? acc[2].y : acc[3].y;
      o.z = (r == 0) ? acc[0].z : (r == 1) ? acc[1].z : (r == 2) ? acc[2].z : acc[3].z;
      o.w = (r == 0) ? acc[0].w : (r == 1) ? acc[1].w : (r == 2) ? acc[2].w : acc[3].w;
      *(float4*)&ctx[(size_t)(b * SS + row0 + r) * DD + h * 32 + 4 * d2] = o;
    }
  }
}

// ---------------------------------------------------------------------------
__global__ void k_emis(const float* __restrict__ X, const float* __restrict__ Wtag,
                       const float* __restrict__ btag, float* __restrict__ em) {
  int idx = blockIdx.x * 256 + threadIdx.x;
  if (idx >= NN * TT) return;
  int n = idx / TT, t = idx - n * TT;
  const float* xr = X + (size_t)n * DD;
  const float* wr = Wtag + (size_t)t * DD;
  float acc = 0.f;
  #pragma unroll
  for (int k = 0; k < DD / 4; k++) {
    float4 x4 = *(const float4*)(xr + 4 * k);
    float4 w4 = *(const float4*)(wr + 4 * k);
    acc += x4.x * w4.x + x4.y * w4.y + x4.z * w4.z + x4.w * w4.w;
  }
  em[idx] = acc + btag[t];
}

// ---------------------------------------------------------------------------
__global__ void k_crf(const float* __restrict__ em, const int* __restrict__ sent,
                      const int* __restrict__ tags, const float* __restrict__ trans,
                      const float* __restrict__ start_t, const float* __restrict__ end_t,
                      float* __restrict__ part) {
  const int b = blockIdx.x;
  const int lane = threadIdx.x;
  const int j = (lane < TT) ? lane : 0;
  float tr[TT];
  #pragma unroll
  for (int i = 0; i < TT; i++) tr[i] = trans[i * TT + j];
  const float* emb_ = em + (size_t)b * SS * TT;
  float fv = start_t[j] + emb_[j];
  for (int s = 1; s < SS; s++) {
    int tok = sent[b * SS + s];
    if (tok != 0) {
      float a[TT];
      #pragma unroll
      for (int i = 0; i < TT; i++) a[i] = __shfl(fv, i) + tr[i];
      float m = a[0];
      #pragma unroll
      for (int i = 1; i < TT; i++) m = fmaxf(m, a[i]);
      float sum = 0.f;
      #pragma unroll
      for (int i = 0; i < TT; i++) sum += expf(a[i] - m);
      fv = emb_[s * TT + j] + m + logf(sum);
    }
  }
  float aa[TT];
  #pragma unroll
  for (int i = 0; i < TT; i++) aa[i] = __shfl(fv, i) + end_t[i];
  float m2 = aa[0];
  #pragma unroll
  for (int i = 1; i < TT; i++) m2 = fmaxf(m2, aa[i]);
  float sum2 = 0.f;
  #pragma unroll
  for (int i = 0; i < TT; i++) sum2 += expf(aa[i] - m2);
  float fwd = m2 + logf(sum2);
  float p = 0.f;
  int cnt = 0;
  #pragma unroll
  for (int ii = 0; ii < 8; ii++) {
    int s = lane + 64 * ii;
    cnt += (sent[b * SS + s] != 0) ? 1 : 0;
    int s2 = s + 1;
    if (s2 < SS && sent[b * SS + s2] != 0) {
      int tp = tags[b * SS + s2 - 1];
      int tc = tags[b * SS + s2];
      p += trans[tp * TT + tc] + emb_[(size_t)s2 * TT + tc];
    }
  }
  #pragma unroll
  for (int off = 32; off >= 1; off >>= 1) {
    p += __shfl_xor(p, off);
    cnt += __shfl_xor(cnt, off);
  }
  if (lane == 0) {
    int t0 = tags[b * SS];
    float score = start_t[t0] + emb_[t0] + p;
    int lastt = tags[b * SS + cnt - 1];
    score += end_t[lastt];
    part[b] = fwd - score;
  }
}

__global__ void k_final(const float* __restrict__ part, float* __restrict__ out) {
  float v = part[threadIdx.x];
  #pragma unroll
  for (int off = 32; off >= 1; off >>= 1) v += __shfl_xor(v, off);
  if (threadIdx.x == 0) out[0] = v * (1.f / 64.f);
}

// ---------------------------------------------------------------------------
extern "C" void kernel_launch(void* const* d_in, const int* in_sizes, int n_in,
                              void* d_out, int out_size, void* d_ws, size_t ws_size,
                              hipStream_t stream) {
  const int*   sent  = (const int*)d_in[0];
  const int*   tags  = (const int*)d_in[1];
  const float* emb   = (const float*)d_in[2];
  const float* Wqkv  = (const float*)d_in[3];
  const float* bqkv  = (const float*)d_in[4];
  const float* Wo    = (const float*)d_in[5];
  const float* bo    = (const float*)d_in[6];
  const float* W1    = (const float*)d_in[7];
  const float* b1f   = (const float*)d_in[8];
  const float* W2    = (const float*)d_in[9];
  const float* b2f   = (const float*)d_in[10];
  const float* ln1g  = (const float*)d_in[11];
  const float* ln1b  = (const float*)d_in[12];
  const float* ln2g  = (const float*)d_in[13];
  const float* ln2b  = (const float*)d_in[14];
  const float* Wtag  = (const float*)d_in[15];
  const float* btag  = (const float*)d_in[16];
  const float* trans = (const float*)d_in[17];
  const float* st    = (const float*)d_in[18];
  const float* et    = (const float*)d_in[19];

  float* ws   = (float*)d_ws;
  float* xA   = ws + OFF_X;
  float* xB   = ws + OFF_Y;
  float* qkv  = ws + OFF_QKV;
  float* ff   = ws + OFF_QKV;
  float* ctx  = ws + OFF_CTX;
  float* Kt   = ws + OFF_KT;
  float* em   = ws + OFF_EM;
  float* part = ws + OFF_PART;
  float* out  = (float*)d_out;

  k_embed<<<NN, DD, 0, stream>>>(sent, emb, xA);

  for (int l = 0; l < LL; l++) {
    k_gemm<128, false><<<dim3(NN / 64, 6), 256, 0, stream>>>(
        xA, Wqkv + (size_t)l * 3 * DD * DD, bqkv + l * 3 * DD, qkv, 3 * DD);
    k_kt<<<dim3(8, BB * HH), 256, 0, stream>>>(qkv, Kt);
    k_attn<<<dim3(2048), 256, 0, stream>>>(qkv, Kt, sent, ctx);
    k_gemm_ln<128><<<dim3(NN / 32), 256, 0, stream>>>(
        ctx, Wo + (size_t)l * DD * DD, bo + l * DD, xA, ln1g + l * DD, ln1b + l * DD, xB);
    k_gemm<128, true><<<dim3(NN / 64, 4), 256, 0, stream>>>(
        xB, W1 + (size_t)l * DFFc * DD, b1f + l * DFFc, ff, DFFc);
    k_gemm_ln<256><<<dim3(NN / 32), 256, 0, stream>>>(
        ff, W2 + (size_t)l * DD * DFFc, b2f + l * DD, xB, ln2g + l * DD, ln2b + l * DD, xA);
  }

  k_emis<<<(NN * TT + 255) / 256, 256, 0, stream>>>(xA, Wtag, btag, em);
  k_crf<<<BB, 64, 0, stream>>>(em, sent, tags, trans, st, et, part);
  k_final<<<1, 64, 0, stream>>>(part, out);
}

// Round 7
// 867.289 us; speedup vs baseline: 3.0125x; 1.7081x over previous
//
#include <hip/hip_runtime.h>

// Problem constants
#define BB   64
#define SS   512
#define DD   128
#define DFFc 256
#define HH   4
#define TT   9
#define LL   2
#define HDc  32
#define NN   (BB*SS)   // 32768 tokens

// Workspace layout (float offsets)
#define OFF_X    0
#define OFF_Y    (NN*DD)            // xB; ALSO reused for Kl/Vl bf16 (dead between gemm_ln2 and gemm_ln1)
#define OFF_QKV  (2*NN*DD)          // 3*NN*DD floats; reused for FF hidden
#define OFF_CTX  (5*NN*DD)
#define OFF_KT   (6*NN*DD)          // Kh/Vh bf16 (2 * NN*DD ushorts = NN*DD floats)
#define OFF_EM   (7*NN*DD)
#define OFF_PART (7*NN*DD + NN*TT)

typedef __attribute__((ext_vector_type(8))) short short8;
typedef __attribute__((ext_vector_type(8))) unsigned short ushort8;
typedef __attribute__((ext_vector_type(4))) float f32x4;

__device__ __forceinline__ unsigned short f2bf(float f) {
  unsigned int u = __float_as_uint(f);
  u += 0x7FFFu + ((u >> 16) & 1u);           // RNE; inputs are finite
  return (unsigned short)(u >> 16);
}
__device__ __forceinline__ float bf2f(unsigned short h) {
  return __uint_as_float(((unsigned int)h) << 16);
}

// ---------------------------------------------------------------------------
__global__ void k_embed(const int* __restrict__ sent, const float* __restrict__ emb,
                        float* __restrict__ x) {
  int n = blockIdx.x;
  int d = threadIdx.x;
  int tok = sent[n];
  int s = n & (SS - 1);
  float e = (tok != 0) ? emb[(size_t)tok * DD + d] : 0.f;
  int i = d >> 1;
  float dv = expf((float)(2 * i) * (-9.210340371976184f / (float)DD));
  float ang = (float)s * dv;
  float pe = (d & 1) ? cosf(ang) : sinf(ang);
  x[(size_t)n * DD + d] = e + pe;
}

// ---------------------------------------------------------------------------
template <int KTOT, bool RELU>
__global__ __launch_bounds__(256) void k_gemm(const float* __restrict__ X,
                                              const float* __restrict__ W,
                                              const float* __restrict__ bias,
                                              float* __restrict__ Y, int ldY) {
  __shared__ float Xs[64][68];
  __shared__ float Wt[64][68];
  const int tid = threadIdx.x;
  const int tx = tid & 15, ty = tid >> 4;
  const int n0 = blockIdx.x * 64, c0g = blockIdx.y * 64;
  float acc[4][4] = {};
  for (int kb = 0; kb < KTOT; kb += 64) {
    #pragma unroll
    for (int p = 0; p < 4; p++) {
      int r = p * 16 + (tid >> 4);
      int c4 = (tid & 15) * 4;
      *(float4*)&Xs[r][c4] = *(const float4*)&X[(size_t)(n0 + r) * KTOT + kb + c4];
    }
    #pragma unroll
    for (int p = 0; p < 4; p++) {
      int c = (tid >> 4) + 16 * p;
      int kk0 = tid & 15;
      #pragma unroll
      for (int ii = 0; ii < 4; ii++)
        Wt[kk0 + 16 * ii][c] = W[(size_t)(c0g + c) * KTOT + kb + kk0 + 16 * ii];
    }
    __syncthreads();
    #pragma unroll
    for (int k4 = 0; k4 < 16; k4++) {
      float4 a4[4], b4[4];
      #pragma unroll
      for (int i = 0; i < 4; i++) a4[i] = *(const float4*)&Xs[4 * ty + i][4 * k4];
      #pragma unroll
      for (int k = 0; k < 4; k++) b4[k] = *(const float4*)&Wt[4 * k4 + k][4 * tx];
      #pragma unroll
      for (int k = 0; k < 4; k++) {
        #pragma unroll
        for (int i = 0; i < 4; i++) {
          float av = (k == 0) ? a4[i].x : (k == 1) ? a4[i].y : (k == 2) ? a4[i].z : a4[i].w;
          acc[i][0] = fmaf(av, b4[k].x, acc[i][0]);
          acc[i][1] = fmaf(av, b4[k].y, acc[i][1]);
          acc[i][2] = fmaf(av, b4[k].z, acc[i][2]);
          acc[i][3] = fmaf(av, b4[k].w, acc[i][3]);
        }
      }
    }
    __syncthreads();
  }
  float4 bi = *(const float4*)&bias[c0g + 4 * tx];
  #pragma unroll
  for (int i = 0; i < 4; i++) {
    float4 o;
    o.x = acc[i][0] + bi.x; o.y = acc[i][1] + bi.y;
    o.z = acc[i][2] + bi.z; o.w = acc[i][3] + bi.w;
    if (RELU) {
      o.x = fmaxf(o.x, 0.f); o.y = fmaxf(o.y, 0.f);
      o.z = fmaxf(o.z, 0.f); o.w = fmaxf(o.w, 0.f);
    }
    *(float4*)&Y[(size_t)(n0 + 4 * ty + i) * ldY + c0g + 4 * tx] = o;
  }
}

// ---------------------------------------------------------------------------
template <int KTOT>
__global__ __launch_bounds__(256) void k_gemm_ln(const float* __restrict__ X,
                                                 const float* __restrict__ W,
                                                 const float* __restrict__ bias,
                                                 const float* __restrict__ Res,
                                                 const float* __restrict__ gam,
                                                 const float* __restrict__ bet,
                                                 float* __restrict__ Y) {
  __shared__ float Xs[32][68];
  __shared__ float Wt[64][132];
  const int tid = threadIdx.x;
  const int tx = tid & 31, ty = tid >> 5;
  const int n0 = blockIdx.x * 32;
  float acc[4][4] = {};
  for (int kb = 0; kb < KTOT; kb += 64) {
    #pragma unroll
    for (int p = 0; p < 2; p++) {
      int r = p * 16 + (tid >> 4);
      int c4 = (tid & 15) * 4;
      *(float4*)&Xs[r][c4] = *(const float4*)&X[(size_t)(n0 + r) * KTOT + kb + c4];
    }
    #pragma unroll
    for (int p = 0; p < 8; p++) {
      int c = (tid >> 4) + 16 * p;
      int kk0 = tid & 15;
      #pragma unroll
      for (int ii = 0; ii < 4; ii++)
        Wt[kk0 + 16 * ii][c] = W[(size_t)c * KTOT + kb + kk0 + 16 * ii];
    }
    __syncthreads();
    #pragma unroll
    for (int k4 = 0; k4 < 16; k4++) {
      float4 a4[4], b4[4];
      #pragma unroll
      for (int i = 0; i < 4; i++) a4[i] = *(const float4*)&Xs[4 * ty + i][4 * k4];
      #pragma unroll
      for (int k = 0; k < 4; k++) b4[k] = *(const float4*)&Wt[4 * k4 + k][4 * tx];
      #pragma unroll
      for (int k = 0; k < 4; k++) {
        #pragma unroll
        for (int i = 0; i < 4; i++) {
          float av = (k == 0) ? a4[i].x : (k == 1) ? a4[i].y : (k == 2) ? a4[i].z : a4[i].w;
          acc[i][0] = fmaf(av, b4[k].x, acc[i][0]);
          acc[i][1] = fmaf(av, b4[k].y, acc[i][1]);
          acc[i][2] = fmaf(av, b4[k].z, acc[i][2]);
          acc[i][3] = fmaf(av, b4[k].w, acc[i][3]);
        }
      }
    }
    __syncthreads();
  }
  const int c0 = 4 * tx;
  float4 bi = *(const float4*)&bias[c0];
  float4 gm = *(const float4*)&gam[c0];
  float4 be = *(const float4*)&bet[c0];
  #pragma unroll
  for (int i = 0; i < 4; i++) {
    int n = n0 + 4 * ty + i;
    float4 rs = *(const float4*)&Res[(size_t)n * DD + c0];
    float v0 = acc[i][0] + bi.x + rs.x;
    float v1 = acc[i][1] + bi.y + rs.y;
    float v2 = acc[i][2] + bi.z + rs.z;
    float v3 = acc[i][3] + bi.w + rs.w;
    float s1 = v0 + v1 + v2 + v3;
    float s2 = v0 * v0 + v1 * v1 + v2 * v2 + v3 * v3;
    #pragma unroll
    for (int off = 16; off >= 1; off >>= 1) {
      s1 += __shfl_xor(s1, off);
      s2 += __shfl_xor(s2, off);
    }
    float mu = s1 * 0.0078125f;
    float var = s2 * 0.0078125f - mu * mu;
    float rstd = rsqrtf(var + 1e-5f);
    float4 o;
    o.x = (v0 - mu) * rstd * gm.x + be.x;
    o.y = (v1 - mu) * rstd * gm.y + be.y;
    o.z = (v2 - mu) * rstd * gm.z + be.z;
    o.w = (v3 - mu) * rstd * gm.w + be.w;
    *(float4*)&Y[(size_t)n * DD + c0] = o;
  }
}

// ---------------------------------------------------------------------------
// Pack K and V of qkv into split-bf16 (hi+lo): Kh/Kl [bh][s][32], Vh/Vl [bh][32][s].
__global__ void k_pack(const float* __restrict__ qkv,
                       unsigned short* __restrict__ Kh, unsigned short* __restrict__ Kl,
                       unsigned short* __restrict__ Vh, unsigned short* __restrict__ Vl) {
  const int st = blockIdx.x * 64;
  const int bh = blockIdx.y;
  const int b = bh >> 2, h = bh & 3;
  const int tid = threadIdx.x;
  __shared__ float tile[64][33];
  #pragma unroll
  for (int p = 0; p < 8; p++) {
    int sl = p * 8 + (tid >> 5);
    int d = tid & 31;
    const float* src = qkv + (size_t)(b * SS + st + sl) * 384 + h * 32 + d;
    float kv = src[128];
    unsigned short khu = f2bf(kv);
    size_t o = (size_t)(bh * SS + st + sl) * 32 + d;
    Kh[o] = khu;
    Kl[o] = f2bf(kv - bf2f(khu));
    tile[sl][d] = src[256];              // V slice to LDS for transpose
  }
  __syncthreads();
  int d = tid >> 3, s0 = (tid & 7) * 8;
  ushort8 vh, vl;
  #pragma unroll
  for (int i = 0; i < 8; i++) {
    float v = tile[s0 + i][d];
    unsigned short hu = f2bf(v);
    vh[i] = hu;
    vl[i] = f2bf(v - bf2f(hu));
  }
  size_t o = (size_t)(bh * 32 + d) * SS + st + s0;
  *(ushort8*)&Vh[o] = vh;
  *(ushort8*)&Vl[o] = vl;
}

// ---------------------------------------------------------------------------
// MFMA attention (split-bf16, 3-term => ~fp32 accuracy).
// Block: 64 q rows, 4 waves x 16 q. XCD swizzle retained (r3 fetch evidence).
// Per wave: QK^T via mfma_16x16x32 (K=32=HD, 1 tile/step), chunked 128 ks;
// softmax WITHOUT max-subtraction (post-LN scores bounded; masked -> exp(-1e9)=0);
// P (hi+lo bf16) staged in per-wave LDS [q][ks]; PV computed transposed:
// ctx^T[d][q] = V^T . P^T so both MFMA operands are direct 16B loads.
__global__ __launch_bounds__(256) void k_attn(const float* __restrict__ qkv,
    const unsigned short* __restrict__ Kh, const unsigned short* __restrict__ Kl,
    const unsigned short* __restrict__ Vh, const unsigned short* __restrict__ Vl,
    const int* __restrict__ sent, float* __restrict__ ctx) {
  const int id = blockIdx.x;
  const int xcd = id & 7, rem = id >> 3;
  const int qt = rem & 7;                 // 0..7
  const int bh = xcd + 8 * (rem >> 3);    // 0..255
  const int b = bh >> 2, h = bh & 3;
  const int tid = threadIdx.x, w = tid >> 6, lane = tid & 63;
  const int l15 = lane & 15, kg = lane >> 4;

  __shared__ float kb_lds[512];
  __shared__ unsigned short Ph[4][16][136];   // [wave][q][ks(128)+pad]
  __shared__ unsigned short Pl[4][16][136];
  __shared__ float l_lds[4][16];

  for (int i = tid; i < 512; i += 256)
    kb_lds[i] = (sent[b * SS + i] != 0) ? 0.f : -1e9f;
  __syncthreads();

  // Q fragment (A: row q = l15, k = d = kg*8..+7), split hi/lo on the fly
  const int qrow = qt * 64 + w * 16 + l15;
  const float* qp = qkv + (size_t)(b * SS + qrow) * 384 + h * 32 + kg * 8;
  short8 qh, ql;
  #pragma unroll
  for (int i = 0; i < 8; i++) {
    float v = qp[i];
    unsigned short hu = f2bf(v);
    qh[i] = (short)hu;
    ql[i] = (short)f2bf(v - bf2f(hu));
  }

  f32x4 acc0 = {0.f, 0.f, 0.f, 0.f};   // ctx^T d-tile 0 (d = kg*4+j, q = l15)
  f32x4 acc1 = {0.f, 0.f, 0.f, 0.f};   // d-tile 1 (d = 16+kg*4+j)
  float ls[4] = {0.f, 0.f, 0.f, 0.f};  // softmax denominators, rows kg*4+j
  const float scale = 0.17677669529663687f; // 1/sqrt(32)

  const unsigned short* KhB = Kh + (size_t)bh * SS * 32;
  const unsigned short* KlB = Kl + (size_t)bh * SS * 32;
  const unsigned short* VhB = Vh + (size_t)bh * 32 * SS;
  const unsigned short* VlB = Vl + (size_t)bh * 32 * SS;

  for (int c = 0; c < 4; c++) {
    const int ksb = c * 128;
    // --- QK^T: 8 tiles of 16 ks, 3-term split ---
    f32x4 sc[8];
    #pragma unroll
    for (int t = 0; t < 8; t++) {
      size_t ko = (size_t)(ksb + t * 16 + l15) * 32 + kg * 8;
      short8 kh_ = *(const short8*)(KhB + ko);
      short8 kl_ = *(const short8*)(KlB + ko);
      f32x4 z = {0.f, 0.f, 0.f, 0.f};
      f32x4 s = __builtin_amdgcn_mfma_f32_16x16x32_bf16(qh, kh_, z, 0, 0, 0);
      s = __builtin_amdgcn_mfma_f32_16x16x32_bf16(qh, kl_, s, 0, 0, 0);
      s = __builtin_amdgcn_mfma_f32_16x16x32_bf16(ql, kh_, s, 0, 0, 0);
      sc[t] = s;
    }
    // --- exp + stage P (hi/lo) ---
    #pragma unroll
    for (int t = 0; t < 8; t++) {
      float kbv = kb_lds[ksb + t * 16 + l15];
      #pragma unroll
      for (int j = 0; j < 4; j++) {
        float s = fmaf(sc[t][j], scale, kbv);
        float p = __expf(s);               // masked: exp(~-1e9) = 0 exactly
        ls[j] += p;
        unsigned short ph = f2bf(p);
        Ph[w][kg * 4 + j][t * 16 + l15] = ph;
        Pl[w][kg * 4 + j][t * 16 + l15] = f2bf(p - bf2f(ph));
      }
    }
    // --- PV (transposed): acc[d][q] += V^T . P^T over this chunk ---
    #pragma unroll
    for (int k4 = 0; k4 < 4; k4++) {
      short8 ph_ = *(const short8*)&Ph[w][l15][k4 * 32 + kg * 8];
      short8 pl_ = *(const short8*)&Pl[w][l15][k4 * 32 + kg * 8];
      size_t vo0 = (size_t)l15 * SS + ksb + k4 * 32 + kg * 8;
      size_t vo1 = (size_t)(16 + l15) * SS + ksb + k4 * 32 + kg * 8;
      short8 vh0 = *(const short8*)(VhB + vo0);
      short8 vl0 = *(const short8*)(VlB + vo0);
      acc0 = __builtin_amdgcn_mfma_f32_16x16x32_bf16(vh0, ph_, acc0, 0, 0, 0);
      acc0 = __builtin_amdgcn_mfma_f32_16x16x32_bf16(vh0, pl_, acc0, 0, 0, 0);
      acc0 = __builtin_amdgcn_mfma_f32_16x16x32_bf16(vl0, ph_, acc0, 0, 0, 0);
      short8 vh1 = *(const short8*)(VhB + vo1);
      short8 vl1 = *(const short8*)(VlB + vo1);
      acc1 = __builtin_amdgcn_mfma_f32_16x16x32_bf16(vh1, ph_, acc1, 0, 0, 0);
      acc1 = __builtin_amdgcn_mfma_f32_16x16x32_bf16(vh1, pl_, acc1, 0, 0, 0);
      acc1 = __builtin_amdgcn_mfma_f32_16x16x32_bf16(vl1, ph_, acc1, 0, 0, 0);
    }
  }
  // denominator: reduce over the 16-lane column groups, redistribute via LDS
  #pragma unroll
  for (int j = 0; j < 4; j++) {
    #pragma unroll
    for (int off = 1; off <= 8; off <<= 1) ls[j] += __shfl_xor(ls[j], off);
  }
  if (l15 == 0) {
    #pragma unroll
    for (int j = 0; j < 4; j++) l_lds[w][kg * 4 + j] = ls[j];
  }
  float linv = 1.f / l_lds[w][l15];      // same-wave LDS dep; compiler inserts wait
  float* cp = ctx + (size_t)(b * SS + qrow) * DD + h * 32;
  #pragma unroll
  for (int j = 0; j < 4; j++) {
    cp[kg * 4 + j] = acc0[j] * linv;
    cp[16 + kg * 4 + j] = acc1[j] * linv;
  }
}

// ---------------------------------------------------------------------------
__global__ void k_emis(const float* __restrict__ X, const float* __restrict__ Wtag,
                       const float* __restrict__ btag, float* __restrict__ em) {
  int idx = blockIdx.x * 256 + threadIdx.x;
  if (idx >= NN * TT) return;
  int n = idx / TT, t = idx - n * TT;
  const float* xr = X + (size_t)n * DD;
  const float* wr = Wtag + (size_t)t * DD;
  float acc = 0.f;
  #pragma unroll
  for (int k = 0; k < DD / 4; k++) {
    float4 x4 = *(const float4*)(xr + 4 * k);
    float4 w4 = *(const float4*)(wr + 4 * k);
    acc += x4.x * w4.x + x4.y * w4.y + x4.z * w4.z + x4.w * w4.w;
  }
  em[idx] = acc + btag[t];
}

// ---------------------------------------------------------------------------
__global__ void k_crf(const float* __restrict__ em, const int* __restrict__ sent,
                      const int* __restrict__ tags, const float* __restrict__ trans,
                      const float* __restrict__ start_t, const float* __restrict__ end_t,
                      float* __restrict__ part) {
  const int b = blockIdx.x;
  const int lane = threadIdx.x;
  const int j = (lane < TT) ? lane : 0;
  float tr[TT];
  #pragma unroll
  for (int i = 0; i < TT; i++) tr[i] = trans[i * TT + j];
  const float* emb_ = em + (size_t)b * SS * TT;
  float fv = start_t[j] + emb_[j];
  for (int s = 1; s < SS; s++) {
    int tok = sent[b * SS + s];
    if (tok != 0) {
      float a[TT];
      #pragma unroll
      for (int i = 0; i < TT; i++) a[i] = __shfl(fv, i) + tr[i];
      float m = a[0];
      #pragma unroll
      for (int i = 1; i < TT; i++) m = fmaxf(m, a[i]);
      float sum = 0.f;
      #pragma unroll
      for (int i = 0; i < TT; i++) sum += expf(a[i] - m);
      fv = emb_[s * TT + j] + m + logf(sum);
    }
  }
  float aa[TT];
  #pragma unroll
  for (int i = 0; i < TT; i++) aa[i] = __shfl(fv, i) + end_t[i];
  float m2 = aa[0];
  #pragma unroll
  for (int i = 1; i < TT; i++) m2 = fmaxf(m2, aa[i]);
  float sum2 = 0.f;
  #pragma unroll
  for (int i = 0; i < TT; i++) sum2 += expf(aa[i] - m2);
  float fwd = m2 + logf(sum2);
  float p = 0.f;
  int cnt = 0;
  #pragma unroll
  for (int ii = 0; ii < 8; ii++) {
    int s = lane + 64 * ii;
    cnt += (sent[b * SS + s] != 0) ? 1 : 0;
    int s2 = s + 1;
    if (s2 < SS && sent[b * SS + s2] != 0) {
      int tp = tags[b * SS + s2 - 1];
      int tc = tags[b * SS + s2];
      p += trans[tp * TT + tc] + emb_[(size_t)s2 * TT + tc];
    }
  }
  #pragma unroll
  for (int off = 32; off >= 1; off >>= 1) {
    p += __shfl_xor(p, off);
    cnt += __shfl_xor(cnt, off);
  }
  if (lane == 0) {
    int t0 = tags[b * SS];
    float score = start_t[t0] + emb_[t0] + p;
    int lastt = tags[b * SS + cnt - 1];
    score += end_t[lastt];
    part[b] = fwd - score;
  }
}

__global__ void k_final(const float* __restrict__ part, float* __restrict__ out) {
  float v = part[threadIdx.x];
  #pragma unroll
  for (int off = 32; off >= 1; off >>= 1) v += __shfl_xor(v, off);
  if (threadIdx.x == 0) out[0] = v * (1.f / 64.f);
}

// ---------------------------------------------------------------------------
extern "C" void kernel_launch(void* const* d_in, const int* in_sizes, int n_in,
                              void* d_out, int out_size, void* d_ws, size_t ws_size,
                              hipStream_t stream) {
  const int*   sent  = (const int*)d_in[0];
  const int*   tags  = (const int*)d_in[1];
  const float* emb   = (const float*)d_in[2];
  const float* Wqkv  = (const float*)d_in[3];
  const float* bqkv  = (const float*)d_in[4];
  const float* Wo    = (const float*)d_in[5];
  const float* bo    = (const float*)d_in[6];
  const float* W1    = (const float*)d_in[7];
  const float* b1f   = (const float*)d_in[8];
  const float* W2    = (const float*)d_in[9];
  const float* b2f   = (const float*)d_in[10];
  const float* ln1g  = (const float*)d_in[11];
  const float* ln1b  = (const float*)d_in[12];
  const float* ln2g  = (const float*)d_in[13];
  const float* ln2b  = (const float*)d_in[14];
  const float* Wtag  = (const float*)d_in[15];
  const float* btag  = (const float*)d_in[16];
  const float* trans = (const float*)d_in[17];
  const float* st    = (const float*)d_in[18];
  const float* et    = (const float*)d_in[19];

  float* ws   = (float*)d_ws;
  float* xA   = ws + OFF_X;
  float* xB   = ws + OFF_Y;
  float* qkv  = ws + OFF_QKV;
  float* ff   = ws + OFF_QKV;
  float* ctx  = ws + OFF_CTX;
  float* em   = ws + OFF_EM;
  float* part = ws + OFF_PART;
  float* out  = (float*)d_out;

  // split-bf16 K/V buffers: hi pair in OFF_KT region, lo pair overlays xB
  // (xB is dead from gemm_ln2 of the previous layer until gemm_ln1 of this one)
  unsigned short* Kh = (unsigned short*)(ws + OFF_KT);
  unsigned short* Vh = Kh + (size_t)NN * DD;
  unsigned short* Kl = (unsigned short*)(ws + OFF_Y);
  unsigned short* Vl = Kl + (size_t)NN * DD;

  k_embed<<<NN, DD, 0, stream>>>(sent, emb, xA);

  for (int l = 0; l < LL; l++) {
    k_gemm<128, false><<<dim3(NN / 64, 6), 256, 0, stream>>>(
        xA, Wqkv + (size_t)l * 3 * DD * DD, bqkv + l * 3 * DD, qkv, 3 * DD);
    k_pack<<<dim3(8, BB * HH), 256, 0, stream>>>(qkv, Kh, Kl, Vh, Vl);
    k_attn<<<dim3(2048), 256, 0, stream>>>(qkv, Kh, Kl, Vh, Vl, sent, ctx);
    k_gemm_ln<128><<<dim3(NN / 32), 256, 0, stream>>>(
        ctx, Wo + (size_t)l * DD * DD, bo + l * DD, xA, ln1g + l * DD, ln1b + l * DD, xB);
    k_gemm<128, true><<<dim3(NN / 64, 4), 256, 0, stream>>>(
        xB, W1 + (size_t)l * DFFc * DD, b1f + l * DFFc, ff, DFFc);
    k_gemm_ln<256><<<dim3(NN / 32), 256, 0, stream>>>(
        ff, W2 + (size_t)l * DD * DFFc, b2f + l * DD, xB, ln2g + l * DD, ln2b + l * DD, xA);
  }

  k_emis<<<(NN * TT + 255) / 256, 256, 0, stream>>>(xA, Wtag, btag, em);
  k_crf<<<BB, 64, 0, stream>>>(em, sent, tags, trans, st, et, part);
  k_final<<<1, 64, 0, stream>>>(part, out);
}

// Round 8
// 675.495 us; speedup vs baseline: 3.8678x; 1.2839x over previous
//
#include <hip/hip_runtime.h>

// Problem constants
#define BB   64
#define SS   512
#define DD   128
#define DFFc 256
#define HH   4
#define TT   9
#define LL   2
#define HDc  32
#define NN   (BB*SS)   // 32768 tokens

// Workspace layout (float offsets)
#define OFF_X    0
#define OFF_Y    (NN*DD)            // xB; ALSO reused for Kl/Vl bf16 (dead between gemm_ln2 and gemm_ln1)
#define OFF_QKV  (2*NN*DD)          // 3*NN*DD floats; reused for FF hidden
#define OFF_CTX  (5*NN*DD)          // ctx; ALSO reused for CRF chunk matrices M (dead after last gemm_ln1)
#define OFF_KT   (6*NN*DD)          // Kh/Vh bf16 (2 * NN*DD ushorts = NN*DD floats)
#define OFF_EM   (7*NN*DD)
#define OFF_PART (7*NN*DD + NN*TT)

typedef __attribute__((ext_vector_type(8))) short short8;
typedef __attribute__((ext_vector_type(8))) unsigned short ushort8;
typedef __attribute__((ext_vector_type(4))) float f32x4;

__device__ __forceinline__ unsigned short f2bf(float f) {
  unsigned int u = __float_as_uint(f);
  u += 0x7FFFu + ((u >> 16) & 1u);           // RNE; inputs are finite
  return (unsigned short)(u >> 16);
}
__device__ __forceinline__ float bf2f(unsigned short h) {
  return __uint_as_float(((unsigned int)h) << 16);
}

// ---------------------------------------------------------------------------
__global__ void k_embed(const int* __restrict__ sent, const float* __restrict__ emb,
                        float* __restrict__ x) {
  int n = blockIdx.x;
  int d = threadIdx.x;
  int tok = sent[n];
  int s = n & (SS - 1);
  float e = (tok != 0) ? emb[(size_t)tok * DD + d] : 0.f;
  int i = d >> 1;
  float dv = expf((float)(2 * i) * (-9.210340371976184f / (float)DD));
  float ang = (float)s * dv;
  float pe = (d & 1) ? cosf(ang) : sinf(ang);
  x[(size_t)n * DD + d] = e + pe;
}

// ---------------------------------------------------------------------------
template <int KTOT, bool RELU>
__global__ __launch_bounds__(256) void k_gemm(const float* __restrict__ X,
                                              const float* __restrict__ W,
                                              const float* __restrict__ bias,
                                              float* __restrict__ Y, int ldY) {
  __shared__ float Xs[64][68];
  __shared__ float Wt[64][68];
  const int tid = threadIdx.x;
  const int tx = tid & 15, ty = tid >> 4;
  const int n0 = blockIdx.x * 64, c0g = blockIdx.y * 64;
  float acc[4][4] = {};
  for (int kb = 0; kb < KTOT; kb += 64) {
    #pragma unroll
    for (int p = 0; p < 4; p++) {
      int r = p * 16 + (tid >> 4);
      int c4 = (tid & 15) * 4;
      *(float4*)&Xs[r][c4] = *(const float4*)&X[(size_t)(n0 + r) * KTOT + kb + c4];
    }
    #pragma unroll
    for (int p = 0; p < 4; p++) {
      int c = (tid >> 4) + 16 * p;
      int kk0 = tid & 15;
      #pragma unroll
      for (int ii = 0; ii < 4; ii++)
        Wt[kk0 + 16 * ii][c] = W[(size_t)(c0g + c) * KTOT + kb + kk0 + 16 * ii];
    }
    __syncthreads();
    #pragma unroll
    for (int k4 = 0; k4 < 16; k4++) {
      float4 a4[4], b4[4];
      #pragma unroll
      for (int i = 0; i < 4; i++) a4[i] = *(const float4*)&Xs[4 * ty + i][4 * k4];
      #pragma unroll
      for (int k = 0; k < 4; k++) b4[k] = *(const float4*)&Wt[4 * k4 + k][4 * tx];
      #pragma unroll
      for (int k = 0; k < 4; k++) {
        #pragma unroll
        for (int i = 0; i < 4; i++) {
          float av = (k == 0) ? a4[i].x : (k == 1) ? a4[i].y : (k == 2) ? a4[i].z : a4[i].w;
          acc[i][0] = fmaf(av, b4[k].x, acc[i][0]);
          acc[i][1] = fmaf(av, b4[k].y, acc[i][1]);
          acc[i][2] = fmaf(av, b4[k].z, acc[i][2]);
          acc[i][3] = fmaf(av, b4[k].w, acc[i][3]);
        }
      }
    }
    __syncthreads();
  }
  float4 bi = *(const float4*)&bias[c0g + 4 * tx];
  #pragma unroll
  for (int i = 0; i < 4; i++) {
    float4 o;
    o.x = acc[i][0] + bi.x; o.y = acc[i][1] + bi.y;
    o.z = acc[i][2] + bi.z; o.w = acc[i][3] + bi.w;
    if (RELU) {
      o.x = fmaxf(o.x, 0.f); o.y = fmaxf(o.y, 0.f);
      o.z = fmaxf(o.z, 0.f); o.w = fmaxf(o.w, 0.f);
    }
    *(float4*)&Y[(size_t)(n0 + 4 * ty + i) * ldY + c0g + 4 * tx] = o;
  }
}

// ---------------------------------------------------------------------------
template <int KTOT>
__global__ __launch_bounds__(256) void k_gemm_ln(const float* __restrict__ X,
                                                 const float* __restrict__ W,
                                                 const float* __restrict__ bias,
                                                 const float* __restrict__ Res,
                                                 const float* __restrict__ gam,
                                                 const float* __restrict__ bet,
                                                 float* __restrict__ Y) {
  __shared__ float Xs[32][68];
  __shared__ float Wt[64][132];
  const int tid = threadIdx.x;
  const int tx = tid & 31, ty = tid >> 5;
  const int n0 = blockIdx.x * 32;
  float acc[4][4] = {};
  for (int kb = 0; kb < KTOT; kb += 64) {
    #pragma unroll
    for (int p = 0; p < 2; p++) {
      int r = p * 16 + (tid >> 4);
      int c4 = (tid & 15) * 4;
      *(float4*)&Xs[r][c4] = *(const float4*)&X[(size_t)(n0 + r) * KTOT + kb + c4];
    }
    #pragma unroll
    for (int p = 0; p < 8; p++) {
      int c = (tid >> 4) + 16 * p;
      int kk0 = tid & 15;
      #pragma unroll
      for (int ii = 0; ii < 4; ii++)
        Wt[kk0 + 16 * ii][c] = W[(size_t)c * KTOT + kb + kk0 + 16 * ii];
    }
    __syncthreads();
    #pragma unroll
    for (int k4 = 0; k4 < 16; k4++) {
      float4 a4[4], b4[4];
      #pragma unroll
      for (int i = 0; i < 4; i++) a4[i] = *(const float4*)&Xs[4 * ty + i][4 * k4];
      #pragma unroll
      for (int k = 0; k < 4; k++) b4[k] = *(const float4*)&Wt[4 * k4 + k][4 * tx];
      #pragma unroll
      for (int k = 0; k < 4; k++) {
        #pragma unroll
        for (int i = 0; i < 4; i++) {
          float av = (k == 0) ? a4[i].x : (k == 1) ? a4[i].y : (k == 2) ? a4[i].z : a4[i].w;
          acc[i][0] = fmaf(av, b4[k].x, acc[i][0]);
          acc[i][1] = fmaf(av, b4[k].y, acc[i][1]);
          acc[i][2] = fmaf(av, b4[k].z, acc[i][2]);
          acc[i][3] = fmaf(av, b4[k].w, acc[i][3]);
        }
      }
    }
    __syncthreads();
  }
  const int c0 = 4 * tx;
  float4 bi = *(const float4*)&bias[c0];
  float4 gm = *(const float4*)&gam[c0];
  float4 be = *(const float4*)&bet[c0];
  #pragma unroll
  for (int i = 0; i < 4; i++) {
    int n = n0 + 4 * ty + i;
    float4 rs = *(const float4*)&Res[(size_t)n * DD + c0];
    float v0 = acc[i][0] + bi.x + rs.x;
    float v1 = acc[i][1] + bi.y + rs.y;
    float v2 = acc[i][2] + bi.z + rs.z;
    float v3 = acc[i][3] + bi.w + rs.w;
    float s1 = v0 + v1 + v2 + v3;
    float s2 = v0 * v0 + v1 * v1 + v2 * v2 + v3 * v3;
    #pragma unroll
    for (int off = 16; off >= 1; off >>= 1) {
      s1 += __shfl_xor(s1, off);
      s2 += __shfl_xor(s2, off);
    }
    float mu = s1 * 0.0078125f;
    float var = s2 * 0.0078125f - mu * mu;
    float rstd = rsqrtf(var + 1e-5f);
    float4 o;
    o.x = (v0 - mu) * rstd * gm.x + be.x;
    o.y = (v1 - mu) * rstd * gm.y + be.y;
    o.z = (v2 - mu) * rstd * gm.z + be.z;
    o.w = (v3 - mu) * rstd * gm.w + be.w;
    *(float4*)&Y[(size_t)n * DD + c0] = o;
  }
}

// ---------------------------------------------------------------------------
// Pack K and V of qkv into split-bf16 (hi+lo): Kh/Kl [bh][s][32], Vh/Vl [bh][32][s].
__global__ void k_pack(const float* __restrict__ qkv,
                       unsigned short* __restrict__ Kh, unsigned short* __restrict__ Kl,
                       unsigned short* __restrict__ Vh, unsigned short* __restrict__ Vl) {
  const int st = blockIdx.x * 64;
  const int bh = blockIdx.y;
  const int b = bh >> 2, h = bh & 3;
  const int tid = threadIdx.x;
  __shared__ float tile[64][33];
  #pragma unroll
  for (int p = 0; p < 8; p++) {
    int sl = p * 8 + (tid >> 5);
    int d = tid & 31;
    const float* src = qkv + (size_t)(b * SS + st + sl) * 384 + h * 32 + d;
    float kv = src[128];
    unsigned short khu = f2bf(kv);
    size_t o = (size_t)(bh * SS + st + sl) * 32 + d;
    Kh[o] = khu;
    Kl[o] = f2bf(kv - bf2f(khu));
    tile[sl][d] = src[256];              // V slice to LDS for transpose
  }
  __syncthreads();
  int d = tid >> 3, s0 = (tid & 7) * 8;
  ushort8 vh, vl;
  #pragma unroll
  for (int i = 0; i < 8; i++) {
    float v = tile[s0 + i][d];
    unsigned short hu = f2bf(v);
    vh[i] = hu;
    vl[i] = f2bf(v - bf2f(hu));
  }
  size_t o = (size_t)(bh * 32 + d) * SS + st + s0;
  *(ushort8*)&Vh[o] = vh;
  *(ushort8*)&Vl[o] = vl;
}

// ---------------------------------------------------------------------------
// MFMA attention (split-bf16, 3-term => ~fp32 accuracy). See r5-r7 notes.
__global__ __launch_bounds__(256) void k_attn(const float* __restrict__ qkv,
    const unsigned short* __restrict__ Kh, const unsigned short* __restrict__ Kl,
    const unsigned short* __restrict__ Vh, const unsigned short* __restrict__ Vl,
    const int* __restrict__ sent, float* __restrict__ ctx) {
  const int id = blockIdx.x;
  const int xcd = id & 7, rem = id >> 3;
  const int qt = rem & 7;                 // 0..7
  const int bh = xcd + 8 * (rem >> 3);    // 0..255
  const int b = bh >> 2, h = bh & 3;
  const int tid = threadIdx.x, w = tid >> 6, lane = tid & 63;
  const int l15 = lane & 15, kg = lane >> 4;

  __shared__ float kb_lds[512];
  __shared__ unsigned short Ph[4][16][136];   // [wave][q][ks(128)+pad]
  __shared__ unsigned short Pl[4][16][136];
  __shared__ float l_lds[4][16];

  for (int i = tid; i < 512; i += 256)
    kb_lds[i] = (sent[b * SS + i] != 0) ? 0.f : -1e9f;
  __syncthreads();

  const int qrow = qt * 64 + w * 16 + l15;
  const float* qp = qkv + (size_t)(b * SS + qrow) * 384 + h * 32 + kg * 8;
  short8 qh, ql;
  #pragma unroll
  for (int i = 0; i < 8; i++) {
    float v = qp[i];
    unsigned short hu = f2bf(v);
    qh[i] = (short)hu;
    ql[i] = (short)f2bf(v - bf2f(hu));
  }

  f32x4 acc0 = {0.f, 0.f, 0.f, 0.f};
  f32x4 acc1 = {0.f, 0.f, 0.f, 0.f};
  float ls[4] = {0.f, 0.f, 0.f, 0.f};
  const float scale = 0.17677669529663687f; // 1/sqrt(32)

  const unsigned short* KhB = Kh + (size_t)bh * SS * 32;
  const unsigned short* KlB = Kl + (size_t)bh * SS * 32;
  const unsigned short* VhB = Vh + (size_t)bh * 32 * SS;
  const unsigned short* VlB = Vl + (size_t)bh * 32 * SS;

  for (int c = 0; c < 4; c++) {
    const int ksb = c * 128;
    f32x4 sc[8];
    #pragma unroll
    for (int t = 0; t < 8; t++) {
      size_t ko = (size_t)(ksb + t * 16 + l15) * 32 + kg * 8;
      short8 kh_ = *(const short8*)(KhB + ko);
      short8 kl_ = *(const short8*)(KlB + ko);
      f32x4 z = {0.f, 0.f, 0.f, 0.f};
      f32x4 s = __builtin_amdgcn_mfma_f32_16x16x32_bf16(qh, kh_, z, 0, 0, 0);
      s = __builtin_amdgcn_mfma_f32_16x16x32_bf16(qh, kl_, s, 0, 0, 0);
      s = __builtin_amdgcn_mfma_f32_16x16x32_bf16(ql, kh_, s, 0, 0, 0);
      sc[t] = s;
    }
    #pragma unroll
    for (int t = 0; t < 8; t++) {
      float kbv = kb_lds[ksb + t * 16 + l15];
      #pragma unroll
      for (int j = 0; j < 4; j++) {
        float s = fmaf(sc[t][j], scale, kbv);
        float p = __expf(s);
        ls[j] += p;
        unsigned short ph = f2bf(p);
        Ph[w][kg * 4 + j][t * 16 + l15] = ph;
        Pl[w][kg * 4 + j][t * 16 + l15] = f2bf(p - bf2f(ph));
      }
    }
    #pragma unroll
    for (int k4 = 0; k4 < 4; k4++) {
      short8 ph_ = *(const short8*)&Ph[w][l15][k4 * 32 + kg * 8];
      short8 pl_ = *(const short8*)&Pl[w][l15][k4 * 32 + kg * 8];
      size_t vo0 = (size_t)l15 * SS + ksb + k4 * 32 + kg * 8;
      size_t vo1 = (size_t)(16 + l15) * SS + ksb + k4 * 32 + kg * 8;
      short8 vh0 = *(const short8*)(VhB + vo0);
      short8 vl0 = *(const short8*)(VlB + vo0);
      acc0 = __builtin_amdgcn_mfma_f32_16x16x32_bf16(vh0, ph_, acc0, 0, 0, 0);
      acc0 = __builtin_amdgcn_mfma_f32_16x16x32_bf16(vh0, pl_, acc0, 0, 0, 0);
      acc0 = __builtin_amdgcn_mfma_f32_16x16x32_bf16(vl0, ph_, acc0, 0, 0, 0);
      short8 vh1 = *(const short8*)(VhB + vo1);
      short8 vl1 = *(const short8*)(VlB + vo1);
      acc1 = __builtin_amdgcn_mfma_f32_16x16x32_bf16(vh1, ph_, acc1, 0, 0, 0);
      acc1 = __builtin_amdgcn_mfma_f32_16x16x32_bf16(vh1, pl_, acc1, 0, 0, 0);
      acc1 = __builtin_amdgcn_mfma_f32_16x16x32_bf16(vl1, ph_, acc1, 0, 0, 0);
    }
  }
  #pragma unroll
  for (int j = 0; j < 4; j++) {
    #pragma unroll
    for (int off = 1; off <= 8; off <<= 1) ls[j] += __shfl_xor(ls[j], off);
  }
  if (l15 == 0) {
    #pragma unroll
    for (int j = 0; j < 4; j++) l_lds[w][kg * 4 + j] = ls[j];
  }
  float linv = 1.f / l_lds[w][l15];
  float* cp = ctx + (size_t)(b * SS + qrow) * DD + h * 32;
  #pragma unroll
  for (int j = 0; j < 4; j++) {
    cp[kg * 4 + j] = acc0[j] * linv;
    cp[16 + kg * 4 + j] = acc1[j] * linv;
  }
}

// ---------------------------------------------------------------------------
__global__ void k_emis(const float* __restrict__ X, const float* __restrict__ Wtag,
                       const float* __restrict__ btag, float* __restrict__ em) {
  int idx = blockIdx.x * 256 + threadIdx.x;
  if (idx >= NN * TT) return;
  int n = idx / TT, t = idx - n * TT;
  const float* xr = X + (size_t)n * DD;
  const float* wr = Wtag + (size_t)t * DD;
  float acc = 0.f;
  #pragma unroll
  for (int k = 0; k < DD / 4; k++) {
    float4 x4 = *(const float4*)(xr + 4 * k);
    float4 w4 = *(const float4*)(wr + 4 * k);
    acc += x4.x * w4.x + x4.y * w4.y + x4.z * w4.z + x4.w * w4.w;
  }
  em[idx] = acc + btag[t];
}

// ---------------------------------------------------------------------------
// CRF as log-semiring matrix scan.
// The recursion fv <- fv (x) M_s (M_s[i][j] = trans[i][j] + em_s[j]; masked
// step = identity) is associative. k_crf_scan computes row i of each 64-step
// chunk product by scanning the basis vector e_i (identical 9-lane update to
// the old serial kernel) -> 9x8x64 = 4608 independent waves (was 64).
// k_crf_comb folds fv0 through the 8 chunk matrices (8 steps, not 511).
// Fast __expf/__logf: single v_exp/v_log vs libm sequences (latency-bound).
__global__ void k_crf_scan(const float* __restrict__ em, const int* __restrict__ sent,
                           const float* __restrict__ trans, float* __restrict__ M) {
  const int i = blockIdx.x;     // row 0..8
  const int c = blockIdx.y;     // chunk 0..7
  const int b = blockIdx.z;     // batch
  const int lane = threadIdx.x; // 64
  const int j = (lane < TT) ? lane : 0;
  float tr[TT];
  #pragma unroll
  for (int k = 0; k < TT; k++) tr[k] = trans[k * TT + j];
  const float* emb_ = em + (size_t)b * SS * TT;
  float v = (j == i) ? 0.f : -1e30f;       // basis row e_i (log-space)
  const int s0 = 1 + c * 64;
  const int s1 = (s0 + 64 < SS) ? s0 + 64 : SS;
  for (int s = s0; s < s1; s++) {
    int tok = sent[b * SS + s];            // uniform across wave
    if (tok != 0) {
      float a[TT];
      #pragma unroll
      for (int k = 0; k < TT; k++) a[k] = __shfl(v, k) + tr[k];
      float m = a[0];
      #pragma unroll
      for (int k = 1; k < TT; k++) m = fmaxf(m, a[k]);
      float sum = 0.f;
      #pragma unroll
      for (int k = 0; k < TT; k++) sum += __expf(a[k] - m);
      v = emb_[s * TT + j] + m + __logf(sum);
    }
  }
  if (lane < TT) M[(((size_t)b * 8 + c) * TT + i) * TT + j] = v;
}

__global__ void k_crf_comb(const float* __restrict__ em, const int* __restrict__ sent,
                           const int* __restrict__ tags, const float* __restrict__ trans,
                           const float* __restrict__ start_t, const float* __restrict__ end_t,
                           const float* __restrict__ M, float* __restrict__ part) {
  const int b = blockIdx.x;
  const int lane = threadIdx.x;
  const int j = (lane < TT) ? lane : 0;
  const float* emb_ = em + (size_t)b * SS * TT;
  float fv = start_t[j] + emb_[j];
  #pragma unroll
  for (int c = 0; c < 8; c++) {
    const float* Mc = M + (((size_t)b * 8 + c) * TT) * TT;
    float a[TT];
    #pragma unroll
    for (int k = 0; k < TT; k++) a[k] = __shfl(fv, k) + Mc[k * TT + j];
    float m = a[0];
    #pragma unroll
    for (int k = 1; k < TT; k++) m = fmaxf(m, a[k]);
    float sum = 0.f;
    #pragma unroll
    for (int k = 0; k < TT; k++) sum += __expf(a[k] - m);
    fv = m + __logf(sum);                  // em already folded into M
  }
  float aa[TT];
  #pragma unroll
  for (int i = 0; i < TT; i++) aa[i] = __shfl(fv, i) + end_t[i];
  float m2 = aa[0];
  #pragma unroll
  for (int i = 1; i < TT; i++) m2 = fmaxf(m2, aa[i]);
  float sum2 = 0.f;
  #pragma unroll
  for (int i = 0; i < TT; i++) sum2 += __expf(aa[i] - m2);
  float fwd = m2 + __logf(sum2);
  // gold path score, parallel over positions
  float p = 0.f;
  int cnt = 0;
  #pragma unroll
  for (int ii = 0; ii < 8; ii++) {
    int s = lane + 64 * ii;
    cnt += (sent[b * SS + s] != 0) ? 1 : 0;
    int s2 = s + 1;
    if (s2 < SS && sent[b * SS + s2] != 0) {
      int tp = tags[b * SS + s2 - 1];
      int tc = tags[b * SS + s2];
      p += trans[tp * TT + tc] + emb_[(size_t)s2 * TT + tc];
    }
  }
  #pragma unroll
  for (int off = 32; off >= 1; off >>= 1) {
    p += __shfl_xor(p, off);
    cnt += __shfl_xor(cnt, off);
  }
  if (lane == 0) {
    int t0 = tags[b * SS];
    float score = start_t[t0] + emb_[t0] + p;
    int lastt = tags[b * SS + cnt - 1];
    score += end_t[lastt];
    part[b] = fwd - score;
  }
}

__global__ void k_final(const float* __restrict__ part, float* __restrict__ out) {
  float v = part[threadIdx.x];
  #pragma unroll
  for (int off = 32; off >= 1; off >>= 1) v += __shfl_xor(v, off);
  if (threadIdx.x == 0) out[0] = v * (1.f / 64.f);
}

// ---------------------------------------------------------------------------
extern "C" void kernel_launch(void* const* d_in, const int* in_sizes, int n_in,
                              void* d_out, int out_size, void* d_ws, size_t ws_size,
                              hipStream_t stream) {
  const int*   sent  = (const int*)d_in[0];
  const int*   tags  = (const int*)d_in[1];
  const float* emb   = (const float*)d_in[2];
  const float* Wqkv  = (const float*)d_in[3];
  const float* bqkv  = (const float*)d_in[4];
  const float* Wo    = (const float*)d_in[5];
  const float* bo    = (const float*)d_in[6];
  const float* W1    = (const float*)d_in[7];
  const float* b1f   = (const float*)d_in[8];
  const float* W2    = (const float*)d_in[9];
  const float* b2f   = (const float*)d_in[10];
  const float* ln1g  = (const float*)d_in[11];
  const float* ln1b  = (const float*)d_in[12];
  const float* ln2g  = (const float*)d_in[13];
  const float* ln2b  = (const float*)d_in[14];
  const float* Wtag  = (const float*)d_in[15];
  const float* btag  = (const float*)d_in[16];
  const float* trans = (const float*)d_in[17];
  const float* st    = (const float*)d_in[18];
  const float* et    = (const float*)d_in[19];

  float* ws   = (float*)d_ws;
  float* xA   = ws + OFF_X;
  float* xB   = ws + OFF_Y;
  float* qkv  = ws + OFF_QKV;
  float* ff   = ws + OFF_QKV;
  float* ctx  = ws + OFF_CTX;
  float* em   = ws + OFF_EM;
  float* part = ws + OFF_PART;
  float* out  = (float*)d_out;

  // split-bf16 K/V buffers: hi pair in OFF_KT region, lo pair overlays xB
  unsigned short* Kh = (unsigned short*)(ws + OFF_KT);
  unsigned short* Vh = Kh + (size_t)NN * DD;
  unsigned short* Kl = (unsigned short*)(ws + OFF_Y);
  unsigned short* Vl = Kl + (size_t)NN * DD;
  // CRF chunk matrices overlay the (dead-by-then) ctx region: 64*8*81 floats
  float* Mbuf = ws + OFF_CTX;

  k_embed<<<NN, DD, 0, stream>>>(sent, emb, xA);

  for (int l = 0; l < LL; l++) {
    k_gemm<128, false><<<dim3(NN / 64, 6), 256, 0, stream>>>(
        xA, Wqkv + (size_t)l * 3 * DD * DD, bqkv + l * 3 * DD, qkv, 3 * DD);
    k_pack<<<dim3(8, BB * HH), 256, 0, stream>>>(qkv, Kh, Kl, Vh, Vl);
    k_attn<<<dim3(2048), 256, 0, stream>>>(qkv, Kh, Kl, Vh, Vl, sent, ctx);
    k_gemm_ln<128><<<dim3(NN / 32), 256, 0, stream>>>(
        ctx, Wo + (size_t)l * DD * DD, bo + l * DD, xA, ln1g + l * DD, ln1b + l * DD, xB);
    k_gemm<128, true><<<dim3(NN / 64, 4), 256, 0, stream>>>(
        xB, W1 + (size_t)l * DFFc * DD, b1f + l * DFFc, ff, DFFc);
    k_gemm_ln<256><<<dim3(NN / 32), 256, 0, stream>>>(
        ff, W2 + (size_t)l * DD * DFFc, b2f + l * DD, xB, ln2g + l * DD, ln2b + l * DD, xA);
  }

  k_emis<<<(NN * TT + 255) / 256, 256, 0, stream>>>(xA, Wtag, btag, em);
  k_crf_scan<<<dim3(TT, 8, BB), 64, 0, stream>>>(em, sent, trans, Mbuf);
  k_crf_comb<<<BB, 64, 0, stream>>>(em, sent, tags, trans, st, et, Mbuf, part);
  k_final<<<1, 64, 0, stream>>>(part, out);
}